// Round 1
// baseline (3193.042 us; speedup 1.0000x reference)
//
#include <hip/hip_runtime.h>
#include <math.h>

#define S_LEN 4096
#define HID   2048
#define NH    16
#define HD    128
#define NKV   2048
#define NQKV  6144

// ---------- index build: inverse hilbert map + kv gather indices ----------
__global__ void k_build_idx(const int* __restrict__ hmap, int* __restrict__ inv,
                            int* __restrict__ gidx) {
  int i = blockIdx.x * 256 + threadIdx.x;
  if (i < S_LEN) inv[hmap[i]] = i;
  if (i < NKV)   gidx[i] = hmap[2 * i];
}

// ---------- fp32 NT GEMM: C[m,n] = sum_k A[ar(m),k] * B[n,k] ----------
// BM=BN=128, BK=16, 256 threads, 8x8 microtile (split 4+4 rows/cols for bank-free b128 reads)
template<int BM, int BN, int BK>
__global__ __launch_bounds__(256)
void k_gemm_nt(const float* __restrict__ A, const float* __restrict__ B,
               float* __restrict__ C, int M, int N, int K,
               const int* __restrict__ arow)
{
  __shared__ float As[BK][BM];
  __shared__ float Bs[BK][BN];
  const int tid = threadIdx.x;
  const int m0 = blockIdx.y * BM, n0 = blockIdx.x * BN;
  const int tr = tid / 16, tc = tid % 16;

  float acc[8][8];
#pragma unroll
  for (int i = 0; i < 8; ++i)
#pragma unroll
    for (int j = 0; j < 8; ++j) acc[i][j] = 0.f;

  for (int k0 = 0; k0 < K; k0 += BK) {
    // stage A,B tiles: 128 rows x 16 k each; 512 float4 per matrix
#pragma unroll
    for (int f = tid; f < (BM * BK) / 4; f += 256) {
      int row = f >> 2, kq = (f & 3) * 4;
      int ra = arow ? arow[m0 + row] : (m0 + row);
      float4 va = *(const float4*)&A[(size_t)ra * K + k0 + kq];
      As[kq + 0][row] = va.x; As[kq + 1][row] = va.y;
      As[kq + 2][row] = va.z; As[kq + 3][row] = va.w;
      float4 vb = *(const float4*)&B[(size_t)(n0 + row) * K + k0 + kq];
      Bs[kq + 0][row] = vb.x; Bs[kq + 1][row] = vb.y;
      Bs[kq + 2][row] = vb.z; Bs[kq + 3][row] = vb.w;
    }
    __syncthreads();
#pragma unroll
    for (int kk = 0; kk < BK; ++kk) {
      float4 a0 = *(const float4*)&As[kk][4 * tr];
      float4 a1 = *(const float4*)&As[kk][64 + 4 * tr];
      float4 b0 = *(const float4*)&Bs[kk][4 * tc];
      float4 b1 = *(const float4*)&Bs[kk][64 + 4 * tc];
      float a[8] = {a0.x, a0.y, a0.z, a0.w, a1.x, a1.y, a1.z, a1.w};
      float b[8] = {b0.x, b0.y, b0.z, b0.w, b1.x, b1.y, b1.z, b1.w};
#pragma unroll
      for (int i = 0; i < 8; ++i)
#pragma unroll
        for (int j = 0; j < 8; ++j) acc[i][j] += a[i] * b[j];
    }
    __syncthreads();
  }

#pragma unroll
  for (int i = 0; i < 8; ++i) {
    int rl = (i < 4) ? (4 * tr + i) : (64 + 4 * tr + (i - 4));
    float* cb = &C[(size_t)(m0 + rl) * N + n0];
    float4 o0 = {acc[i][0], acc[i][1], acc[i][2], acc[i][3]};
    float4 o1 = {acc[i][4], acc[i][5], acc[i][6], acc[i][7]};
    *(float4*)&cb[4 * tc]      = o0;
    *(float4*)&cb[64 + 4 * tc] = o1;
  }
}

// ---------- flash attention over gathered KV ----------
// block = 256 threads = (32 q-rows) x (8 lanes/row); kv tiles of 32
__global__ __launch_bounds__(256)
void k_attn(const float* __restrict__ qkv, const int* __restrict__ gidx,
            float* __restrict__ att)
{
  __shared__ float Qs[32][132];
  __shared__ float KVs[32][132];
  __shared__ float Ps[32][36];
  const int tid = threadIdx.x;
  const int h  = blockIdx.x / (S_LEN / 32);
  const int q0 = (blockIdx.x % (S_LEN / 32)) * 32;
  const int r = tid >> 3, c = tid & 7;
  const float scale = 0.088388347648318447f; // 1/sqrt(128)

  // stage Q tile (row r staged/read by the same 8 lanes)
  {
    const float* qb = qkv + (size_t)(q0 + r) * NQKV + h * HD;
#pragma unroll
    for (int w = 0; w < 4; ++w)
      *(float4*)&Qs[r][4 * (c + 8 * w)] = *(const float4*)&qb[4 * (c + 8 * w)];
  }

  float4 acc4[4];
#pragma unroll
  for (int u = 0; u < 4; ++u) acc4[u] = make_float4(0.f, 0.f, 0.f, 0.f);
  float m_r = -INFINITY, l_r = 0.f;

  for (int t = 0; t < NKV / 32; ++t) {
    __syncthreads();               // protect KVs (prev PV) and Ps reuse
    const int grow = gidx[t * 32 + r];
    { // stage K tile
      const float* kb = qkv + (size_t)grow * NQKV + HID + h * HD;
#pragma unroll
      for (int w = 0; w < 4; ++w)
        *(float4*)&KVs[r][4 * (c + 8 * w)] = *(const float4*)&kb[4 * (c + 8 * w)];
    }
    __syncthreads();
    // scores: thread (r,c) -> kv cols j = c + 8*jo
    float s[4] = {0.f, 0.f, 0.f, 0.f};
    for (int d4 = 0; d4 < HD; d4 += 4) {
      float4 q4 = *(const float4*)&Qs[r][d4];
#pragma unroll
      for (int jo = 0; jo < 4; ++jo) {
        float4 k4 = *(const float4*)&KVs[c + 8 * jo][d4];
        s[jo] += q4.x * k4.x + q4.y * k4.y + q4.z * k4.z + q4.w * k4.w;
      }
    }
#pragma unroll
    for (int jo = 0; jo < 4; ++jo) s[jo] *= scale;
    // online softmax (row = 8 lanes)
    float mloc = fmaxf(fmaxf(s[0], s[1]), fmaxf(s[2], s[3]));
#pragma unroll
    for (int off = 1; off < 8; off <<= 1) mloc = fmaxf(mloc, __shfl_xor(mloc, off, 8));
    float m_new = fmaxf(m_r, mloc);
    float corr = __expf(m_r - m_new);
    float p[4], psum = 0.f;
#pragma unroll
    for (int jo = 0; jo < 4; ++jo) { p[jo] = __expf(s[jo] - m_new); psum += p[jo]; }
#pragma unroll
    for (int off = 1; off < 8; off <<= 1) psum += __shfl_xor(psum, off, 8);
    l_r = l_r * corr + psum;
    m_r = m_new;
#pragma unroll
    for (int jo = 0; jo < 4; ++jo) Ps[r][c + 8 * jo] = p[jo];
#pragma unroll
    for (int u = 0; u < 4; ++u) {
      acc4[u].x *= corr; acc4[u].y *= corr; acc4[u].z *= corr; acc4[u].w *= corr;
    }
    __syncthreads();               // done reading K
    { // stage V tile into same buffer
      const float* vb = qkv + (size_t)grow * NQKV + 2 * HID + h * HD;
#pragma unroll
      for (int w = 0; w < 4; ++w)
        *(float4*)&KVs[r][4 * (c + 8 * w)] = *(const float4*)&vb[4 * (c + 8 * w)];
    }
    __syncthreads();
    // PV: thread owns d = 4*(c+8u)+{0..3}
    for (int j = 0; j < 32; ++j) {
      float pj = Ps[r][j];
#pragma unroll
      for (int u = 0; u < 4; ++u) {
        float4 v4 = *(const float4*)&KVs[j][4 * (c + 8 * u)];
        acc4[u].x += pj * v4.x; acc4[u].y += pj * v4.y;
        acc4[u].z += pj * v4.z; acc4[u].w += pj * v4.w;
      }
    }
  }

  const float rl = 1.0f / l_r;
  float* ob = att + (size_t)(q0 + r) * HID + h * HD;
#pragma unroll
  for (int u = 0; u < 4; ++u) {
    float4 o = {acc4[u].x * rl, acc4[u].y * rl, acc4[u].z * rl, acc4[u].w * rl};
    *(float4*)&ob[4 * (c + 8 * u)] = o;
  }
}

extern "C" void kernel_launch(void* const* d_in, const int* in_sizes, int n_in,
                              void* d_out, int out_size, void* d_ws, size_t ws_size,
                              hipStream_t stream)
{
  const float* x     = (const float*)d_in[0];
  const float* w_qkv = (const float*)d_in[1];
  const float* w_out = (const float*)d_in[2];
  const int*   hmap  = (const int*)d_in[3];
  float* out = (float*)d_out;

  float* qkv = (float*)d_ws;                                  // 4096 x 6144
  float* att = qkv + (size_t)S_LEN * NQKV;                    // 4096 x 2048
  int*   inv = (int*)(att + (size_t)S_LEN * HID);             // 4096
  int*   gidx = inv + S_LEN;                                  // 2048

  k_build_idx<<<16, 256, 0, stream>>>(hmap, inv, gidx);

  dim3 g1(NQKV / 128, S_LEN / 128);
  k_gemm_nt<128, 128, 16><<<g1, 256, 0, stream>>>(x, w_qkv, qkv, S_LEN, NQKV, HID, nullptr);

  k_attn<<<NH * (S_LEN / 32), 256, 0, stream>>>(qkv, gidx, att);

  dim3 g3(HID / 128, S_LEN / 128);
  k_gemm_nt<128, 128, 16><<<g3, 256, 0, stream>>>(att, w_out, out, S_LEN, HID, HID, inv);
}

// Round 2
// 1895.516 us; speedup vs baseline: 1.6845x; 1.6845x over previous
//
#include <hip/hip_runtime.h>
#include <math.h>

#define S_LEN 4096
#define HID   2048
#define NH    16
#define HD    128
#define NKV   2048
#define NQKV  6144
#define KT    64
#define QBLK  64

typedef __attribute__((ext_vector_type(8))) short bf16x8;
typedef __attribute__((ext_vector_type(4))) float f32x4;

__device__ __forceinline__ ushort f2b(float f) {
  union { float f; unsigned u; } v; v.f = f;
  unsigned u = v.u;
  return (ushort)((u + 0x7fffu + ((u >> 16) & 1u)) >> 16);
}

// ---------- index build ----------
__global__ void k_build_idx(const int* __restrict__ hmap, int* __restrict__ inv,
                            int* __restrict__ gidx) {
  int i = blockIdx.x * 256 + threadIdx.x;
  if (i < S_LEN) inv[hmap[i]] = i;
  if (i < NKV)   gidx[i] = hmap[2 * i];
}

// ---------- fp32 NT GEMM (unchanged) ----------
template<int BM, int BN, int BK>
__global__ __launch_bounds__(256)
void k_gemm_nt(const float* __restrict__ A, const float* __restrict__ B,
               float* __restrict__ C, int M, int N, int K,
               const int* __restrict__ arow)
{
  __shared__ float As[BK][BM];
  __shared__ float Bs[BK][BN];
  const int tid = threadIdx.x;
  const int m0 = blockIdx.y * BM, n0 = blockIdx.x * BN;
  const int tr = tid / 16, tc = tid % 16;

  float acc[8][8];
#pragma unroll
  for (int i = 0; i < 8; ++i)
#pragma unroll
    for (int j = 0; j < 8; ++j) acc[i][j] = 0.f;

  for (int k0 = 0; k0 < K; k0 += BK) {
#pragma unroll
    for (int f = tid; f < (BM * BK) / 4; f += 256) {
      int row = f >> 2, kq = (f & 3) * 4;
      int ra = arow ? arow[m0 + row] : (m0 + row);
      float4 va = *(const float4*)&A[(size_t)ra * K + k0 + kq];
      As[kq + 0][row] = va.x; As[kq + 1][row] = va.y;
      As[kq + 2][row] = va.z; As[kq + 3][row] = va.w;
      float4 vb = *(const float4*)&B[(size_t)(n0 + row) * K + k0 + kq];
      Bs[kq + 0][row] = vb.x; Bs[kq + 1][row] = vb.y;
      Bs[kq + 2][row] = vb.z; Bs[kq + 3][row] = vb.w;
    }
    __syncthreads();
#pragma unroll
    for (int kk = 0; kk < BK; ++kk) {
      float4 a0 = *(const float4*)&As[kk][4 * tr];
      float4 a1 = *(const float4*)&As[kk][64 + 4 * tr];
      float4 b0 = *(const float4*)&Bs[kk][4 * tc];
      float4 b1 = *(const float4*)&Bs[kk][64 + 4 * tc];
      float a[8] = {a0.x, a0.y, a0.z, a0.w, a1.x, a1.y, a1.z, a1.w};
      float b[8] = {b0.x, b0.y, b0.z, b0.w, b1.x, b1.y, b1.z, b1.w};
#pragma unroll
      for (int i = 0; i < 8; ++i)
#pragma unroll
        for (int j = 0; j < 8; ++j) acc[i][j] += a[i] * b[j];
    }
    __syncthreads();
  }

#pragma unroll
  for (int i = 0; i < 8; ++i) {
    int rl = (i < 4) ? (4 * tr + i) : (64 + 4 * tr + (i - 4));
    float* cb = &C[(size_t)(m0 + rl) * N + n0];
    float4 o0 = {acc[i][0], acc[i][1], acc[i][2], acc[i][3]};
    float4 o1 = {acc[i][4], acc[i][5], acc[i][6], acc[i][7]};
    *(float4*)&cb[4 * tc]      = o0;
    *(float4*)&cb[64 + 4 * tc] = o1;
  }
}

// ---------- MFMA flash attention over gathered KV ----------
// 256 threads = 4 waves; wave w owns q-rows [q0+16w, q0+16w+16); KV tiles of 64.
// LDS: K [64][128]bf16 swizzled @0 (16KB); Vt [128][64]bf16 swizzled @16384 (16KB);
//      P per-wave [16][64]bf16 swizzled @32768+w*2048 (8KB). Total 40KB.
__global__ __launch_bounds__(256, 2)
void k_attn_mfma(const float* __restrict__ qkv, const int* __restrict__ gidx,
                 float* __restrict__ att)
{
  __shared__ char lds[40960];
  const int tid  = threadIdx.x;
  const int w    = tid >> 6, lane = tid & 63;
  const int h    = blockIdx.x / (S_LEN / QBLK);
  const int q0   = (blockIdx.x % (S_LEN / QBLK)) * QBLK;
  const int l15  = lane & 15, l4 = lane >> 4;
  const float scale = 0.088388347648318447f; // 1/sqrt(128)

  // ---- preload Q fragments (A operand: row = lane&15, k = (lane>>4)*8+e)
  bf16x8 qf[4];
  {
    const int qrow = q0 + w * 16 + l15;
    const float* qb = qkv + (size_t)qrow * NQKV + h * HD + l4 * 8;
#pragma unroll
    for (int ks = 0; ks < 4; ++ks) {
      float4 a = *(const float4*)(qb + 32 * ks);
      float4 b = *(const float4*)(qb + 32 * ks + 4);
      bf16x8 f;
      f[0] = f2b(a.x); f[1] = f2b(a.y); f[2] = f2b(a.z); f[3] = f2b(a.w);
      f[4] = f2b(b.x); f[5] = f2b(b.y); f[6] = f2b(b.z); f[7] = f2b(b.w);
      qf[ks] = f;
    }
  }

  f32x4 acc[8];
#pragma unroll
  for (int dt = 0; dt < 8; ++dt) acc[dt] = (f32x4){0.f, 0.f, 0.f, 0.f};
  float m[4] = {-INFINITY, -INFINITY, -INFINITY, -INFINITY};
  float l[4] = {0.f, 0.f, 0.f, 0.f};

  const int pbase = 32768 + w * 2048;

  for (int t = 0; t < NKV / KT; ++t) {
    __syncthreads();   // all waves done reading K/Vt of previous tile
    // ---- stage K tile [64][128] bf16, XOR-swizzled
#pragma unroll
    for (int kk = 0; kk < 4; ++kk) {
      int c = tid + 256 * kk;
      int r = c >> 4, ci = c & 15;
      int grow = gidx[t * KT + r];
      const float* kb = qkv + (size_t)grow * NQKV + HID + h * HD + 8 * ci;
      float4 a = *(const float4*)kb;
      float4 b = *(const float4*)(kb + 4);
      bf16x8 f;
      f[0] = f2b(a.x); f[1] = f2b(a.y); f[2] = f2b(a.z); f[3] = f2b(a.w);
      f[4] = f2b(b.x); f[5] = f2b(b.y); f[6] = f2b(b.z); f[7] = f2b(b.w);
      int addr = (r * 256 + 16 * ci) ^ ((r & 7) << 4);
      *(bf16x8*)(lds + addr) = f;
    }
    // ---- stage Vt [128][64] bf16 (transposed), XOR-swizzled
    {
      int j0 = (tid & 31) * 2;
      int d0 = (tid >> 5) * 16;
      int g0 = gidx[t * KT + j0], g1 = gidx[t * KT + j0 + 1];
      const float* v0 = qkv + (size_t)g0 * NQKV + 2 * HID + h * HD + d0;
      const float* v1 = qkv + (size_t)g1 * NQKV + 2 * HID + h * HD + d0;
      float va[16], vb[16];
#pragma unroll
      for (int q = 0; q < 4; ++q) {
        float4 x0 = ((const float4*)v0)[q];
        float4 x1 = ((const float4*)v1)[q];
        va[4*q+0] = x0.x; va[4*q+1] = x0.y; va[4*q+2] = x0.z; va[4*q+3] = x0.w;
        vb[4*q+0] = x1.x; vb[4*q+1] = x1.y; vb[4*q+2] = x1.z; vb[4*q+3] = x1.w;
      }
#pragma unroll
      for (int dd = 0; dd < 16; ++dd) {
        int d = d0 + dd;
        unsigned pk = (unsigned)f2b(va[dd]) | ((unsigned)f2b(vb[dd]) << 16);
        int addr = 16384 + ((d * 128 + 2 * j0) ^ ((d & 7) << 4));
        *(unsigned*)(lds + addr) = pk;
      }
    }
    __syncthreads();

    // ---- QK^T: S tiles jt=0..3, k-steps ks=0..3
    f32x4 s[4];
#pragma unroll
    for (int jt = 0; jt < 4; ++jt) {
      f32x4 ss = (f32x4){0.f, 0.f, 0.f, 0.f};
#pragma unroll
      for (int ks = 0; ks < 4; ++ks) {
        int j = jt * 16 + l15;
        int addr = (j * 256 + 64 * ks + 16 * l4) ^ ((j & 7) << 4);
        bf16x8 kf = *(const bf16x8*)(lds + addr);
        ss = __builtin_amdgcn_mfma_f32_16x16x32_bf16(qf[ks], kf, ss, 0, 0, 0);
      }
      s[jt] = ss;
    }

    // ---- online softmax (row i = 4*(lane>>4)+e lives in 16-lane group)
    float mn[4], corr[4];
#pragma unroll
    for (int e = 0; e < 4; ++e) {
      float v = fmaxf(fmaxf(s[0][e], s[1][e]), fmaxf(s[2][e], s[3][e])) * scale;
      v = fmaxf(v, __shfl_xor(v, 1));
      v = fmaxf(v, __shfl_xor(v, 2));
      v = fmaxf(v, __shfl_xor(v, 4));
      v = fmaxf(v, __shfl_xor(v, 8));
      mn[e] = fmaxf(m[e], v);
      corr[e] = __expf(m[e] - mn[e]);
    }
    float ps[4] = {0.f, 0.f, 0.f, 0.f};
#pragma unroll
    for (int jt = 0; jt < 4; ++jt) {
#pragma unroll
      for (int e = 0; e < 4; ++e) {
        float p = __expf(fmaf(s[jt][e], scale, -mn[e]));
        ps[e] += p;
        int i = 4 * l4 + e;
        int addr = pbase + ((i * 128 + 32 * jt + 2 * l15) ^ ((i & 7) << 4));
        *(ushort*)(lds + addr) = f2b(p);
      }
    }
#pragma unroll
    for (int e = 0; e < 4; ++e) {
      float sp = ps[e];
      sp += __shfl_xor(sp, 1);
      sp += __shfl_xor(sp, 2);
      sp += __shfl_xor(sp, 4);
      sp += __shfl_xor(sp, 8);
      l[e] = l[e] * corr[e] + sp;
      m[e] = mn[e];
#pragma unroll
      for (int dt = 0; dt < 8; ++dt) acc[dt][e] *= corr[e];
    }

    // ---- PV: A = P (per-wave LDS), B = Vt
    bf16x8 pf[2];
#pragma unroll
    for (int ks2 = 0; ks2 < 2; ++ks2) {
      int i = l15;
      int addr = pbase + ((i * 128 + 64 * ks2 + 16 * l4) ^ ((i & 7) << 4));
      pf[ks2] = *(const bf16x8*)(lds + addr);
    }
#pragma unroll
    for (int dt = 0; dt < 8; ++dt) {
#pragma unroll
      for (int ks2 = 0; ks2 < 2; ++ks2) {
        int d = dt * 16 + l15;
        int addr = 16384 + ((d * 128 + 64 * ks2 + 16 * l4) ^ ((d & 7) << 4));
        bf16x8 vf = *(const bf16x8*)(lds + addr);
        acc[dt] = __builtin_amdgcn_mfma_f32_16x16x32_bf16(pf[ks2], vf, acc[dt], 0, 0, 0);
      }
    }
  }

  // ---- epilogue: normalize and write att (fp32)
  float rl[4];
#pragma unroll
  for (int e = 0; e < 4; ++e) rl[e] = 1.0f / l[e];
#pragma unroll
  for (int dt = 0; dt < 8; ++dt) {
#pragma unroll
    for (int e = 0; e < 4; ++e) {
      int i = 4 * l4 + e;
      int row = q0 + w * 16 + i;
      att[(size_t)row * HID + h * HD + dt * 16 + l15] = acc[dt][e] * rl[e];
    }
  }
}

extern "C" void kernel_launch(void* const* d_in, const int* in_sizes, int n_in,
                              void* d_out, int out_size, void* d_ws, size_t ws_size,
                              hipStream_t stream)
{
  const float* x     = (const float*)d_in[0];
  const float* w_qkv = (const float*)d_in[1];
  const float* w_out = (const float*)d_in[2];
  const int*   hmap  = (const int*)d_in[3];
  float* out = (float*)d_out;

  float* qkv = (float*)d_ws;                                  // 4096 x 6144
  float* att = qkv + (size_t)S_LEN * NQKV;                    // 4096 x 2048
  int*   inv = (int*)(att + (size_t)S_LEN * HID);             // 4096
  int*   gidx = inv + S_LEN;                                  // 2048

  k_build_idx<<<16, 256, 0, stream>>>(hmap, inv, gidx);

  dim3 g1(NQKV / 128, S_LEN / 128);
  k_gemm_nt<128, 128, 16><<<g1, 256, 0, stream>>>(x, w_qkv, qkv, S_LEN, NQKV, HID, nullptr);

  k_attn_mfma<<<NH * (S_LEN / QBLK), 256, 0, stream>>>(qkv, gidx, att);

  dim3 g3(HID / 128, S_LEN / 128);
  k_gemm_nt<128, 128, 16><<<g3, 256, 0, stream>>>(att, w_out, out, S_LEN, HID, HID, inv);
}

// Round 3
// 538.567 us; speedup vs baseline: 5.9288x; 3.5196x over previous
//
#include <hip/hip_runtime.h>
#include <math.h>

#define S_LEN 4096
#define HID   2048
#define NH    16
#define HD    128
#define NKV   2048
#define NQKV  6144
#define KT    64
#define QBLK  64

typedef __attribute__((ext_vector_type(8))) _Float16 half8;
typedef __attribute__((ext_vector_type(8))) unsigned short ushort8;
typedef __attribute__((ext_vector_type(4))) float f32x4;

#define GLB_AS __attribute__((address_space(1)))
#define LDS_AS __attribute__((address_space(3)))

__device__ __forceinline__ void gload16(const void* g, void* l) {
  __builtin_amdgcn_global_load_lds((GLB_AS const void*)g, (LDS_AS void*)l, 16, 0, 0);
}

// ---------- index build ----------
__global__ void k_build_idx(const int* __restrict__ hmap, int* __restrict__ gidx) {
  int i = blockIdx.x * 256 + threadIdx.x;
  if (i < NKV) gidx[i] = hmap[2 * i];
}

// ---------- fp32 -> fp16 conversion (vectorized) ----------
__global__ void k_cvt_f16(const float* __restrict__ src, _Float16* __restrict__ dst, int n8) {
  int i = blockIdx.x * 256 + threadIdx.x;
  if (i < n8) {
    float4 a = ((const float4*)src)[2 * i];
    float4 b = ((const float4*)src)[2 * i + 1];
    half8 h;
    h[0] = (_Float16)a.x; h[1] = (_Float16)a.y; h[2] = (_Float16)a.z; h[3] = (_Float16)a.w;
    h[4] = (_Float16)b.x; h[5] = (_Float16)b.y; h[6] = (_Float16)b.z; h[7] = (_Float16)b.w;
    ((half8*)dst)[i] = h;
  }
}

// ---------- fp16 MFMA NT GEMM: C[m,n] = sum_k A[m,k]*B[n,k] ----------
// 128x128 tile, BK=32, 256 threads = 4 waves (2x2), m97 structure w/ global_load_lds.
template<bool OUT_F32>
__global__ __launch_bounds__(256)
void k_gemm_f16(const _Float16* __restrict__ A, const _Float16* __restrict__ B,
                void* __restrict__ Cv, int M, int N, int K)
{
  __shared__ __align__(16) _Float16 As[128 * 32];
  __shared__ __align__(16) _Float16 Bs[128 * 32];
  const int tid = threadIdx.x;
  const int w = tid >> 6, lane = tid & 63;
  const int l15 = lane & 15, l4 = lane >> 4;
  const int m0 = blockIdx.y * 128, n0 = blockIdx.x * 128;
  const int wr = w >> 1, wc = w & 1;

  // staging: wave w, granule q in {0,1}: LDS bytes [(q*4+w)*1024 + lane*16)
  // linear byte L -> row = L/64, k-halves = (L%64)/2
  const int rQ0 = w * 16 + (lane >> 2);
  const int rQ1 = 64 + w * 16 + (lane >> 2);
  const int kb  = (lane & 3) * 8;
  const _Float16* Ag0 = A + (size_t)(m0 + rQ0) * K + kb;
  const _Float16* Ag1 = A + (size_t)(m0 + rQ1) * K + kb;
  const _Float16* Bg0 = B + (size_t)(n0 + rQ0) * K + kb;
  const _Float16* Bg1 = B + (size_t)(n0 + rQ1) * K + kb;
  char* AsB = (char*)As;
  char* BsB = (char*)Bs;

  f32x4 acc[4][4];
#pragma unroll
  for (int i = 0; i < 4; ++i)
#pragma unroll
    for (int j = 0; j < 4; ++j) acc[i][j] = (f32x4){0.f, 0.f, 0.f, 0.f};

  for (int k0 = 0; k0 < K; k0 += 32) {
    gload16(Ag0 + k0, AsB + w * 1024);
    gload16(Ag1 + k0, AsB + (4 + w) * 1024);
    gload16(Bg0 + k0, BsB + w * 1024);
    gload16(Bg1 + k0, BsB + (4 + w) * 1024);
    __syncthreads();

    half8 af[4], bf[4];
#pragma unroll
    for (int mi = 0; mi < 4; ++mi) {
      int row = wr * 64 + mi * 16 + l15;
      af[mi] = *(const half8*)(AsB + row * 64 + l4 * 16);
    }
#pragma unroll
    for (int ni = 0; ni < 4; ++ni) {
      int row = wc * 64 + ni * 16 + l15;
      bf[ni] = *(const half8*)(BsB + row * 64 + l4 * 16);
    }
#pragma unroll
    for (int mi = 0; mi < 4; ++mi)
#pragma unroll
      for (int ni = 0; ni < 4; ++ni)
        acc[mi][ni] = __builtin_amdgcn_mfma_f32_16x16x32_f16(af[mi], bf[ni], acc[mi][ni], 0, 0, 0);
    __syncthreads();
  }

  // epilogue: D row = (lane>>4)*4+e, col = lane&15
  const int rbase = m0 + wr * 64 + l4 * 4;
  const int cbase = n0 + wc * 64 + l15;
#pragma unroll
  for (int mi = 0; mi < 4; ++mi)
#pragma unroll
    for (int ni = 0; ni < 4; ++ni)
#pragma unroll
      for (int e = 0; e < 4; ++e) {
        size_t idx = (size_t)(rbase + mi * 16 + e) * N + cbase + ni * 16;
        if (OUT_F32) ((float*)Cv)[idx] = acc[mi][ni][e];
        else ((_Float16*)Cv)[idx] = (_Float16)acc[mi][ni][e];
      }
}

// ---------- f16 MFMA flash attention over gathered KV ----------
// 256 threads = 4 waves; wave w owns q-rows [q0+16w, +16); KV tiles of 64.
// Output rows scattered by hmap (folds reference scatter into attn epilogue).
__global__ __launch_bounds__(256, 2)
void k_attn_mfma(const _Float16* __restrict__ qkv, const int* __restrict__ gidx,
                 const int* __restrict__ hmap, _Float16* __restrict__ att)
{
  __shared__ __align__(16) char lds[40960];
  const int tid  = threadIdx.x;
  const int w    = tid >> 6, lane = tid & 63;
  const int h    = blockIdx.x / (S_LEN / QBLK);
  const int q0   = (blockIdx.x % (S_LEN / QBLK)) * QBLK;
  const int l15  = lane & 15, l4 = lane >> 4;
  const float scale = 0.088388347648318447f; // 1/sqrt(128)

  // ---- preload Q fragments (A operand: row = lane&15, k = (lane>>4)*8+e)
  half8 qf[4];
  {
    const int qrow = q0 + w * 16 + l15;
    const _Float16* qb = qkv + (size_t)qrow * NQKV + h * HD + l4 * 8;
#pragma unroll
    for (int ks = 0; ks < 4; ++ks) qf[ks] = *(const half8*)(qb + 32 * ks);
  }

  f32x4 acc[8];
#pragma unroll
  for (int dt = 0; dt < 8; ++dt) acc[dt] = (f32x4){0.f, 0.f, 0.f, 0.f};
  float m[4] = {-INFINITY, -INFINITY, -INFINITY, -INFINITY};
  float l[4] = {0.f, 0.f, 0.f, 0.f};

  const int pbase = 32768 + w * 2048;

  for (int t = 0; t < NKV / KT; ++t) {
    __syncthreads();   // all waves done reading K/Vt of previous tile
    // ---- stage K tile [64][128] f16, XOR-swizzled
#pragma unroll
    for (int kk = 0; kk < 4; ++kk) {
      int c = tid + 256 * kk;
      int r = c >> 4, ci = c & 15;
      int grow = gidx[t * KT + r];
      half8 f = *(const half8*)(qkv + (size_t)grow * NQKV + HID + h * HD + 8 * ci);
      int addr = (r * 256 + 16 * ci) ^ ((r & 7) << 4);
      *(half8*)(lds + addr) = f;
    }
    // ---- stage Vt [128][64] f16 (transposed), XOR-swizzled
    {
      int j0 = (tid & 31) * 2;
      int d0 = (tid >> 5) * 16;
      int g0 = gidx[t * KT + j0], g1 = gidx[t * KT + j0 + 1];
      const ushort* v0 = (const ushort*)(qkv + (size_t)g0 * NQKV + 2 * HID + h * HD + d0);
      const ushort* v1 = (const ushort*)(qkv + (size_t)g1 * NQKV + 2 * HID + h * HD + d0);
      ushort8 a0 = ((const ushort8*)v0)[0], a1 = ((const ushort8*)v0)[1];
      ushort8 b0 = ((const ushort8*)v1)[0], b1 = ((const ushort8*)v1)[1];
      ushort va[16], vb[16];
#pragma unroll
      for (int q = 0; q < 8; ++q) { va[q] = a0[q]; va[8 + q] = a1[q]; vb[q] = b0[q]; vb[8 + q] = b1[q]; }
#pragma unroll
      for (int dd = 0; dd < 16; ++dd) {
        int d = d0 + dd;
        unsigned pk = (unsigned)va[dd] | ((unsigned)vb[dd] << 16);
        int addr = 16384 + ((d * 128 + 2 * j0) ^ ((d & 7) << 4));
        *(unsigned*)(lds + addr) = pk;
      }
    }
    __syncthreads();

    // ---- QK^T
    f32x4 s[4];
#pragma unroll
    for (int jt = 0; jt < 4; ++jt) {
      f32x4 ss = (f32x4){0.f, 0.f, 0.f, 0.f};
#pragma unroll
      for (int ks = 0; ks < 4; ++ks) {
        int j = jt * 16 + l15;
        int addr = (j * 256 + 64 * ks + 16 * l4) ^ ((j & 7) << 4);
        half8 kf = *(const half8*)(lds + addr);
        ss = __builtin_amdgcn_mfma_f32_16x16x32_f16(qf[ks], kf, ss, 0, 0, 0);
      }
      s[jt] = ss;
    }

    // ---- online softmax (row i = 4*(lane>>4)+e lives in 16-lane group)
    float mn[4], corr[4];
#pragma unroll
    for (int e = 0; e < 4; ++e) {
      float v = fmaxf(fmaxf(s[0][e], s[1][e]), fmaxf(s[2][e], s[3][e])) * scale;
      v = fmaxf(v, __shfl_xor(v, 1));
      v = fmaxf(v, __shfl_xor(v, 2));
      v = fmaxf(v, __shfl_xor(v, 4));
      v = fmaxf(v, __shfl_xor(v, 8));
      mn[e] = fmaxf(m[e], v);
      corr[e] = __expf(m[e] - mn[e]);
    }
    float ps[4] = {0.f, 0.f, 0.f, 0.f};
#pragma unroll
    for (int jt = 0; jt < 4; ++jt) {
#pragma unroll
      for (int e = 0; e < 4; ++e) {
        float p = __expf(fmaf(s[jt][e], scale, -mn[e]));
        ps[e] += p;
        int i = 4 * l4 + e;
        int addr = pbase + ((i * 128 + 32 * jt + 2 * l15) ^ ((i & 7) << 4));
        *(_Float16*)(lds + addr) = (_Float16)p;
      }
    }
#pragma unroll
    for (int e = 0; e < 4; ++e) {
      float sp = ps[e];
      sp += __shfl_xor(sp, 1);
      sp += __shfl_xor(sp, 2);
      sp += __shfl_xor(sp, 4);
      sp += __shfl_xor(sp, 8);
      l[e] = l[e] * corr[e] + sp;
      m[e] = mn[e];
#pragma unroll
      for (int dt = 0; dt < 8; ++dt) acc[dt][e] *= corr[e];
    }

    // ---- PV: A = P (per-wave LDS), B = Vt
    half8 pf[2];
#pragma unroll
    for (int ks2 = 0; ks2 < 2; ++ks2) {
      int i = l15;
      int addr = pbase + ((i * 128 + 64 * ks2 + 16 * l4) ^ ((i & 7) << 4));
      pf[ks2] = *(const half8*)(lds + addr);
    }
#pragma unroll
    for (int dt = 0; dt < 8; ++dt) {
#pragma unroll
      for (int ks2 = 0; ks2 < 2; ++ks2) {
        int d = dt * 16 + l15;
        int addr = 16384 + ((d * 128 + 64 * ks2 + 16 * l4) ^ ((d & 7) << 4));
        half8 vf = *(const half8*)(lds + addr);
        acc[dt] = __builtin_amdgcn_mfma_f32_16x16x32_f16(pf[ks2], vf, acc[dt], 0, 0, 0);
      }
    }
  }

  // ---- epilogue: normalize, write att f16 at hilbert-scattered row
  float rl[4];
#pragma unroll
  for (int e = 0; e < 4; ++e) rl[e] = 1.0f / l[e];
#pragma unroll
  for (int e = 0; e < 4; ++e) {
    int row = q0 + w * 16 + 4 * l4 + e;
    int srow = hmap[row];
    _Float16* ob = att + (size_t)srow * HID + h * HD + l15;
#pragma unroll
    for (int dt = 0; dt < 8; ++dt) ob[dt * 16] = (_Float16)(acc[dt][e] * rl[e]);
  }
}

extern "C" void kernel_launch(void* const* d_in, const int* in_sizes, int n_in,
                              void* d_out, int out_size, void* d_ws, size_t ws_size,
                              hipStream_t stream)
{
  const float* x     = (const float*)d_in[0];
  const float* w_qkv = (const float*)d_in[1];
  const float* w_out = (const float*)d_in[2];
  const int*   hmap  = (const int*)d_in[3];
  float* out = (float*)d_out;

  char* ws = (char*)d_ws;
  _Float16* x16    = (_Float16*)ws;                              ws += (size_t)S_LEN * HID * 2;
  _Float16* wqkv16 = (_Float16*)ws;                              ws += (size_t)NQKV * HID * 2;
  _Float16* wout16 = (_Float16*)ws;                              ws += (size_t)HID * HID * 2;
  _Float16* qkv16  = (_Float16*)ws;                              ws += (size_t)S_LEN * NQKV * 2;
  _Float16* att16  = (_Float16*)ws;                              ws += (size_t)S_LEN * HID * 2;
  int* gidx = (int*)ws;

  k_build_idx<<<8, 256, 0, stream>>>(hmap, gidx);

  k_cvt_f16<<<(S_LEN * HID / 8 + 255) / 256, 256, 0, stream>>>(x, x16, S_LEN * HID / 8);
  k_cvt_f16<<<(NQKV * HID / 8 + 255) / 256, 256, 0, stream>>>(w_qkv, wqkv16, NQKV * HID / 8);
  k_cvt_f16<<<(HID * HID / 8 + 255) / 256, 256, 0, stream>>>(w_out, wout16, HID * HID / 8);

  dim3 g1(NQKV / 128, S_LEN / 128);
  k_gemm_f16<false><<<g1, 256, 0, stream>>>(x16, wqkv16, qkv16, S_LEN, NQKV, HID);

  k_attn_mfma<<<NH * (S_LEN / QBLK), 256, 0, stream>>>(qkv16, gidx, hmap, att16);

  dim3 g3(HID / 128, S_LEN / 128);
  k_gemm_f16<true><<<g3, 256, 0, stream>>>(att16, wout16, out, S_LEN, HID, HID);
}

// Round 4
// 392.846 us; speedup vs baseline: 8.1280x; 1.3709x over previous
//
#include <hip/hip_runtime.h>
#include <math.h>

#define S_LEN 4096
#define HID   2048
#define NH    16
#define HD    128
#define NKV   2048
#define NQKV  6144
#define KT    64
#define QBLK  128
#define NT    (NKV / KT)
// (1/sqrt(128)) * log2(e) -- folded into Q so QK^T lands in exp2 domain
#define QSCALE 0.12754103668587426f

typedef __attribute__((ext_vector_type(8))) _Float16 half8;
typedef __attribute__((ext_vector_type(4))) float f32x4;

#define GLB_AS __attribute__((address_space(1)))
#define LDS_AS __attribute__((address_space(3)))

__device__ __forceinline__ void gload16(const void* g, void* l) {
  __builtin_amdgcn_global_load_lds((GLB_AS const void*)g, (LDS_AS void*)l, 16, 0, 0);
}

// ---------- index build ----------
__global__ void k_build_idx(const int* __restrict__ hmap, int* __restrict__ gidx) {
  int i = blockIdx.x * 256 + threadIdx.x;
  if (i < NKV) gidx[i] = hmap[2 * i];
}

// ---------- fp32 -> fp16 conversion ----------
__global__ void k_cvt_f16(const float* __restrict__ src, _Float16* __restrict__ dst, int n8) {
  int i = blockIdx.x * 256 + threadIdx.x;
  if (i < n8) {
    float4 a = ((const float4*)src)[2 * i];
    float4 b = ((const float4*)src)[2 * i + 1];
    half8 h;
    h[0] = (_Float16)a.x; h[1] = (_Float16)a.y; h[2] = (_Float16)a.z; h[3] = (_Float16)a.w;
    h[4] = (_Float16)b.x; h[5] = (_Float16)b.y; h[6] = (_Float16)b.z; h[7] = (_Float16)b.w;
    ((half8*)dst)[i] = h;
  }
}

// ---------- fp16 MFMA NT GEMM (unchanged from R3) ----------
template<bool OUT_F32>
__global__ __launch_bounds__(256)
void k_gemm_f16(const _Float16* __restrict__ A, const _Float16* __restrict__ B,
                void* __restrict__ Cv, int M, int N, int K)
{
  __shared__ __align__(16) _Float16 As[128 * 32];
  __shared__ __align__(16) _Float16 Bs[128 * 32];
  const int tid = threadIdx.x;
  const int w = tid >> 6, lane = tid & 63;
  const int l15 = lane & 15, l4 = lane >> 4;
  const int m0 = blockIdx.y * 128, n0 = blockIdx.x * 128;
  const int wr = w >> 1, wc = w & 1;

  const int rQ0 = w * 16 + (lane >> 2);
  const int rQ1 = 64 + w * 16 + (lane >> 2);
  const int kb  = (lane & 3) * 8;
  const _Float16* Ag0 = A + (size_t)(m0 + rQ0) * K + kb;
  const _Float16* Ag1 = A + (size_t)(m0 + rQ1) * K + kb;
  const _Float16* Bg0 = B + (size_t)(n0 + rQ0) * K + kb;
  const _Float16* Bg1 = B + (size_t)(n0 + rQ1) * K + kb;
  char* AsB = (char*)As;
  char* BsB = (char*)Bs;

  f32x4 acc[4][4];
#pragma unroll
  for (int i = 0; i < 4; ++i)
#pragma unroll
    for (int j = 0; j < 4; ++j) acc[i][j] = (f32x4){0.f, 0.f, 0.f, 0.f};

  for (int k0 = 0; k0 < K; k0 += 32) {
    gload16(Ag0 + k0, AsB + w * 1024);
    gload16(Ag1 + k0, AsB + (4 + w) * 1024);
    gload16(Bg0 + k0, BsB + w * 1024);
    gload16(Bg1 + k0, BsB + (4 + w) * 1024);
    __syncthreads();

    half8 af[4], bf[4];
#pragma unroll
    for (int mi = 0; mi < 4; ++mi) {
      int row = wr * 64 + mi * 16 + l15;
      af[mi] = *(const half8*)(AsB + row * 64 + l4 * 16);
    }
#pragma unroll
    for (int ni = 0; ni < 4; ++ni) {
      int row = wc * 64 + ni * 16 + l15;
      bf[ni] = *(const half8*)(BsB + row * 64 + l4 * 16);
    }
#pragma unroll
    for (int mi = 0; mi < 4; ++mi)
#pragma unroll
      for (int ni = 0; ni < 4; ++ni)
        acc[mi][ni] = __builtin_amdgcn_mfma_f32_16x16x32_f16(af[mi], bf[ni], acc[mi][ni], 0, 0, 0);
    __syncthreads();
  }

  const int rbase = m0 + wr * 64 + l4 * 4;
  const int cbase = n0 + wc * 64 + l15;
#pragma unroll
  for (int mi = 0; mi < 4; ++mi)
#pragma unroll
    for (int ni = 0; ni < 4; ++ni)
#pragma unroll
      for (int e = 0; e < 4; ++e) {
        size_t idx = (size_t)(rbase + mi * 16 + e) * N + cbase + ni * 16;
        if (OUT_F32) ((float*)Cv)[idx] = acc[mi][ni][e];
        else ((_Float16*)Cv)[idx] = (_Float16)acc[mi][ni][e];
      }
}

// ---------- prep: build pre-swizzled K / Vt LDS images per (head, kv-tile) ----------
// kimg[h][t]: 16KB image of K tile [64 j][128 d] f16, byte (j*256+2d)^((j&7)<<4)
// vtimg[h][t]: 16KB image of Vt tile [128 d][64 j] f16, byte (d*128+2j)^((d&7)<<4)
__global__ __launch_bounds__(256)
void k_prep(const _Float16* __restrict__ qkv, const int* __restrict__ gidx,
            char* __restrict__ kimg, char* __restrict__ vtimg)
{
  __shared__ _Float16 Vs[64 * 136];
  const int tid = threadIdx.x;
  const int h = blockIdx.x >> 5;
  const int t = blockIdx.x & 31;
  const size_t ibase = (size_t)blockIdx.x * 16384;

#pragma unroll
  for (int it = 0; it < 4; ++it) {
    int idx = tid + 256 * it;           // (j, dblk): 64 x 16
    int j = idx >> 4, dblk = idx & 15;
    int g = gidx[t * KT + j];
    half8 kv = *(const half8*)(qkv + (size_t)g * NQKV + HID + h * HD + dblk * 8);
    *(half8*)(kimg + ibase + ((j * 256 + 16 * dblk) ^ ((j & 7) << 4))) = kv;
    half8 vv = *(const half8*)(qkv + (size_t)g * NQKV + 2 * HID + h * HD + dblk * 8);
    *(half8*)(&Vs[j * 136 + dblk * 8]) = vv;
  }
  __syncthreads();
#pragma unroll
  for (int it = 0; it < 4; ++it) {
    int idx = tid + 256 * it;           // (jblk, d): 8 x 128
    int jblk = idx >> 7, d = idx & 127;
    half8 o;
#pragma unroll
    for (int q = 0; q < 8; ++q) o[q] = Vs[(jblk * 8 + q) * 136 + d];
    *(half8*)(vtimg + ibase + ((d * 128 + 16 * jblk) ^ ((d & 7) << 4))) = o;
  }
}

// ---------- f16 MFMA flash attention, image-staged + double-buffered ----------
// 512 threads = 8 waves, QBLK=128 (16 rows/wave), KV tiles of 64.
// LDS: 2 x (K 16KB + Vt 16KB) @0, P per-wave [16][64]f16 @65536+w*2048. 80KB.
__global__ __launch_bounds__(512, 4)
void k_attn2(const _Float16* __restrict__ qkv, const char* __restrict__ kimg,
             const char* __restrict__ vtimg, const int* __restrict__ hmap,
             _Float16* __restrict__ att)
{
  extern __shared__ __align__(16) char lds[];
  const int tid = threadIdx.x;
  const int w = tid >> 6, lane = tid & 63;
  const int l15 = lane & 15, l4 = lane >> 4;
  const int work = (blockIdx.x & 7) * 64 + (blockIdx.x >> 3);  // XCD-chunked
  const int h  = work >> 5;
  const int q0 = (work & 31) * QBLK;

  // Q fragments, pre-scaled by scale*log2(e)
  half8 qf[4];
  {
    const int qrow = q0 + w * 16 + l15;
    const _Float16* qb = qkv + (size_t)qrow * NQKV + h * HD + l4 * 8;
    const _Float16 qs = (_Float16)QSCALE;
#pragma unroll
    for (int ks = 0; ks < 4; ++ks) {
      half8 v = *(const half8*)(qb + 32 * ks);
#pragma unroll
      for (int q = 0; q < 8; ++q) v[q] *= qs;
      qf[ks] = v;
    }
  }

  const char* kbase = kimg  + (size_t)h * NT * 16384;
  const char* vbase = vtimg + (size_t)h * NT * 16384;

  f32x4 acc[8];
#pragma unroll
  for (int dt = 0; dt < 8; ++dt) acc[dt] = (f32x4){0.f, 0.f, 0.f, 0.f};
  float m[4] = {-1e30f, -1e30f, -1e30f, -1e30f};
  float l[4] = {0.f, 0.f, 0.f, 0.f};
  const int pbase = 65536 + w * 2048;

#define STAGE(buf, t)                                                          \
  do {                                                                         \
    const char* ks_ = kbase + (size_t)(t) * 16384;                             \
    const char* vs_ = vbase + (size_t)(t) * 16384;                             \
    char* d_ = lds + (buf) * 32768;                                            \
    gload16(ks_ + w * 1024 + lane * 16,          d_ + w * 1024);               \
    gload16(ks_ + (8 + w) * 1024 + lane * 16,    d_ + (8 + w) * 1024);         \
    gload16(vs_ + w * 1024 + lane * 16,          d_ + 16384 + w * 1024);       \
    gload16(vs_ + (8 + w) * 1024 + lane * 16,    d_ + 16384 + (8 + w) * 1024); \
  } while (0)

  STAGE(0, 0);
  asm volatile("s_waitcnt vmcnt(0)");
  __syncthreads();

  int cur = 0;
  for (int t = 0; t < NT; ++t) {
    if (t + 1 < NT) STAGE(cur ^ 1, t + 1);
    const char* kl = lds + cur * 32768;
    const char* vl = kl + 16384;

    // QK^T (scores already in log2 domain via Q prescale)
    f32x4 s[4];
#pragma unroll
    for (int jt = 0; jt < 4; ++jt) {
      f32x4 ss = (f32x4){0.f, 0.f, 0.f, 0.f};
#pragma unroll
      for (int ks = 0; ks < 4; ++ks) {
        int j = jt * 16 + l15;
        half8 kf = *(const half8*)(kl + ((j * 256 + 64 * ks + 16 * l4) ^ ((j & 7) << 4)));
        ss = __builtin_amdgcn_mfma_f32_16x16x32_f16(qf[ks], kf, ss, 0, 0, 0);
      }
      s[jt] = ss;
    }

    // tile max per row (row i = 4*l4+e, reduced over 16-lane group)
    float v[4];
#pragma unroll
    for (int e = 0; e < 4; ++e) {
      float x = fmaxf(fmaxf(s[0][e], s[1][e]), fmaxf(s[2][e], s[3][e]));
      x = fmaxf(x, __shfl_xor(x, 1));
      x = fmaxf(x, __shfl_xor(x, 2));
      x = fmaxf(x, __shfl_xor(x, 4));
      x = fmaxf(x, __shfl_xor(x, 8));
      v[e] = x;
    }
    // defer-max: only rescale when max grew by > 8 (log2 units); P <= 256 fits f16
    int need = (v[0] > m[0] + 8.f) | (v[1] > m[1] + 8.f) |
               (v[2] > m[2] + 8.f) | (v[3] > m[3] + 8.f);
    if (__any(need)) {
#pragma unroll
      for (int e = 0; e < 4; ++e) {
        float mn = fmaxf(m[e], v[e]);
        float corr = exp2f(m[e] - mn);
        l[e] *= corr;
        m[e] = mn;
#pragma unroll
        for (int dt = 0; dt < 8; ++dt) acc[dt][e] *= corr;
      }
    }
    float ps[4] = {0.f, 0.f, 0.f, 0.f};
#pragma unroll
    for (int jt = 0; jt < 4; ++jt) {
#pragma unroll
      for (int e = 0; e < 4; ++e) {
        float p = exp2f(s[jt][e] - m[e]);
        ps[e] += p;
        int i = 4 * l4 + e;
        *(_Float16*)(lds + pbase + ((i * 128 + 32 * jt + 2 * l15) ^ ((i & 7) << 4))) = (_Float16)p;
      }
    }
#pragma unroll
    for (int e = 0; e < 4; ++e) {
      float sp = ps[e];
      sp += __shfl_xor(sp, 1);
      sp += __shfl_xor(sp, 2);
      sp += __shfl_xor(sp, 4);
      sp += __shfl_xor(sp, 8);
      l[e] += sp;
    }

    // PV
    half8 pf[2];
#pragma unroll
    for (int ks2 = 0; ks2 < 2; ++ks2)
      pf[ks2] = *(const half8*)(lds + pbase +
                 ((l15 * 128 + 64 * ks2 + 16 * l4) ^ ((l15 & 7) << 4)));
#pragma unroll
    for (int dt = 0; dt < 8; ++dt) {
#pragma unroll
      for (int ks2 = 0; ks2 < 2; ++ks2) {
        int d = dt * 16 + l15;
        half8 vf = *(const half8*)(vl + ((d * 128 + 64 * ks2 + 16 * l4) ^ ((d & 7) << 4)));
        acc[dt] = __builtin_amdgcn_mfma_f32_16x16x32_f16(pf[ks2], vf, acc[dt], 0, 0, 0);
      }
    }

    asm volatile("s_waitcnt vmcnt(0)");
    __syncthreads();
    cur ^= 1;
  }
#undef STAGE

  // epilogue: normalize, scatter rows by hmap
  float rl[4];
#pragma unroll
  for (int e = 0; e < 4; ++e) rl[e] = 1.0f / l[e];
#pragma unroll
  for (int e = 0; e < 4; ++e) {
    int row = q0 + w * 16 + 4 * l4 + e;
    int srow = hmap[row];
    _Float16* ob = att + (size_t)srow * HID + h * HD + l15;
#pragma unroll
    for (int dt = 0; dt < 8; ++dt) ob[dt * 16] = (_Float16)(acc[dt][e] * rl[e]);
  }
}

extern "C" void kernel_launch(void* const* d_in, const int* in_sizes, int n_in,
                              void* d_out, int out_size, void* d_ws, size_t ws_size,
                              hipStream_t stream)
{
  const float* x     = (const float*)d_in[0];
  const float* w_qkv = (const float*)d_in[1];
  const float* w_out = (const float*)d_in[2];
  const int*   hmap  = (const int*)d_in[3];
  float* out = (float*)d_out;

  char* ws = (char*)d_ws;
  int* gidx = (int*)ws;                                          ws += 8192;
  _Float16* x16    = (_Float16*)ws;  // aliased with att16 (x16 dead after GEMM1)
  _Float16* att16  = (_Float16*)ws;                              ws += (size_t)S_LEN * HID * 2;
  _Float16* wqkv16 = (_Float16*)ws;                              ws += (size_t)NQKV * HID * 2;
  _Float16* wout16 = (_Float16*)ws;                              ws += (size_t)HID * HID * 2;
  _Float16* qkv16  = (_Float16*)ws;                              ws += (size_t)S_LEN * NQKV * 2;
  char* kimg  = ws;                                              ws += (size_t)NH * NT * 16384;
  char* vtimg = ws;

  k_build_idx<<<8, 256, 0, stream>>>(hmap, gidx);

  k_cvt_f16<<<(S_LEN * HID / 8 + 255) / 256, 256, 0, stream>>>(x, x16, S_LEN * HID / 8);
  k_cvt_f16<<<(NQKV * HID / 8 + 255) / 256, 256, 0, stream>>>(w_qkv, wqkv16, NQKV * HID / 8);
  k_cvt_f16<<<(HID * HID / 8 + 255) / 256, 256, 0, stream>>>(w_out, wout16, HID * HID / 8);

  dim3 g1(NQKV / 128, S_LEN / 128);
  k_gemm_f16<false><<<g1, 256, 0, stream>>>(x16, wqkv16, qkv16, S_LEN, NQKV, HID);

  k_prep<<<NH * NT, 256, 0, stream>>>(qkv16, gidx, kimg, vtimg);

  k_attn2<<<NH * (S_LEN / QBLK), 512, 81920, stream>>>(qkv16, kimg, vtimg, hmap, att16);

  dim3 g3(HID / 128, S_LEN / 128);
  k_gemm_f16<true><<<g3, 256, 0, stream>>>(att16, wout16, out, S_LEN, HID, HID);
}

// Round 6
// 341.279 us; speedup vs baseline: 9.3561x; 1.1511x over previous
//
#include <hip/hip_runtime.h>
#include <math.h>

#define S_LEN 4096
#define HID   2048
#define NH    16
#define HD    128
#define NKV   2048
#define NQKV  6144
#define KT    64
#define QBLK  128
#define NT    (NKV / KT)
// (1/sqrt(128)) * log2(e) -- folded into Q so QK^T lands in exp2 domain
#define QSCALE 0.12754103668587426f

typedef __attribute__((ext_vector_type(8))) _Float16 half8;
typedef __attribute__((ext_vector_type(4))) _Float16 half4;
typedef __attribute__((ext_vector_type(2))) __fp16 fp16x2;
typedef __attribute__((ext_vector_type(4))) float f32x4;

#define GLB_AS __attribute__((address_space(1)))
#define LDS_AS __attribute__((address_space(3)))

__device__ __forceinline__ void gload16(const void* g, void* l) {
  __builtin_amdgcn_global_load_lds((GLB_AS const void*)g, (LDS_AS void*)l, 16, 0, 0);
}

__device__ __forceinline__ unsigned pkrtz(float a, float b) {
  union { fp16x2 h; unsigned u; } cv;
  cv.h = __builtin_amdgcn_cvt_pkrtz(a, b);
  return cv.u;
}

// ---------- index build ----------
__global__ void k_build_idx(const int* __restrict__ hmap, int* __restrict__ gidx) {
  int i = blockIdx.x * 256 + threadIdx.x;
  if (i < NKV) gidx[i] = hmap[2 * i];
}

// ---------- fp32 -> fp16 conversion ----------
__global__ void k_cvt_f16(const float* __restrict__ src, _Float16* __restrict__ dst, int n8) {
  int i = blockIdx.x * 256 + threadIdx.x;
  if (i < n8) {
    float4 a = ((const float4*)src)[2 * i];
    float4 b = ((const float4*)src)[2 * i + 1];
    half8 h;
    h[0] = (_Float16)a.x; h[1] = (_Float16)a.y; h[2] = (_Float16)a.z; h[3] = (_Float16)a.w;
    h[4] = (_Float16)b.x; h[5] = (_Float16)b.y; h[6] = (_Float16)b.z; h[7] = (_Float16)b.w;
    ((half8*)dst)[i] = h;
  }
}

// ---------- fp16 MFMA NT GEMM (unchanged) ----------
template<bool OUT_F32>
__global__ __launch_bounds__(256)
void k_gemm_f16(const _Float16* __restrict__ A, const _Float16* __restrict__ B,
                void* __restrict__ Cv, int M, int N, int K)
{
  __shared__ __align__(16) _Float16 As[128 * 32];
  __shared__ __align__(16) _Float16 Bs[128 * 32];
  const int tid = threadIdx.x;
  const int w = tid >> 6, lane = tid & 63;
  const int l15 = lane & 15, l4 = lane >> 4;
  const int m0 = blockIdx.y * 128, n0 = blockIdx.x * 128;
  const int wr = w >> 1, wc = w & 1;

  const int rQ0 = w * 16 + (lane >> 2);
  const int rQ1 = 64 + w * 16 + (lane >> 2);
  const int kb  = (lane & 3) * 8;
  const _Float16* Ag0 = A + (size_t)(m0 + rQ0) * K + kb;
  const _Float16* Ag1 = A + (size_t)(m0 + rQ1) * K + kb;
  const _Float16* Bg0 = B + (size_t)(n0 + rQ0) * K + kb;
  const _Float16* Bg1 = B + (size_t)(n0 + rQ1) * K + kb;
  char* AsB = (char*)As;
  char* BsB = (char*)Bs;

  f32x4 acc[4][4];
#pragma unroll
  for (int i = 0; i < 4; ++i)
#pragma unroll
    for (int j = 0; j < 4; ++j) acc[i][j] = (f32x4){0.f, 0.f, 0.f, 0.f};

  for (int k0 = 0; k0 < K; k0 += 32) {
    gload16(Ag0 + k0, AsB + w * 1024);
    gload16(Ag1 + k0, AsB + (4 + w) * 1024);
    gload16(Bg0 + k0, BsB + w * 1024);
    gload16(Bg1 + k0, BsB + (4 + w) * 1024);
    __syncthreads();

    half8 af[4], bf[4];
#pragma unroll
    for (int mi = 0; mi < 4; ++mi) {
      int row = wr * 64 + mi * 16 + l15;
      af[mi] = *(const half8*)(AsB + row * 64 + l4 * 16);
    }
#pragma unroll
    for (int ni = 0; ni < 4; ++ni) {
      int row = wc * 64 + ni * 16 + l15;
      bf[ni] = *(const half8*)(BsB + row * 64 + l4 * 16);
    }
#pragma unroll
    for (int mi = 0; mi < 4; ++mi)
#pragma unroll
      for (int ni = 0; ni < 4; ++ni)
        acc[mi][ni] = __builtin_amdgcn_mfma_f32_16x16x32_f16(af[mi], bf[ni], acc[mi][ni], 0, 0, 0);
    __syncthreads();
  }

  const int rbase = m0 + wr * 64 + l4 * 4;
  const int cbase = n0 + wc * 64 + l15;
#pragma unroll
  for (int mi = 0; mi < 4; ++mi)
#pragma unroll
    for (int ni = 0; ni < 4; ++ni)
#pragma unroll
      for (int e = 0; e < 4; ++e) {
        size_t idx = (size_t)(rbase + mi * 16 + e) * N + cbase + ni * 16;
        if (OUT_F32) ((float*)Cv)[idx] = acc[mi][ni][e];
        else ((_Float16*)Cv)[idx] = (_Float16)acc[mi][ni][e];
      }
}

// ---------- prep: pre-swizzled K / Vt LDS images per (head, kv-tile) ----------
__global__ __launch_bounds__(256)
void k_prep(const _Float16* __restrict__ qkv, const int* __restrict__ gidx,
            char* __restrict__ kimg, char* __restrict__ vtimg)
{
  __shared__ _Float16 Vs[64 * 136];
  const int tid = threadIdx.x;
  const int h = blockIdx.x >> 5;
  const int t = blockIdx.x & 31;
  const size_t ibase = (size_t)blockIdx.x * 16384;

#pragma unroll
  for (int it = 0; it < 4; ++it) {
    int idx = tid + 256 * it;           // (j, dblk): 64 x 16
    int j = idx >> 4, dblk = idx & 15;
    int g = gidx[t * KT + j];
    half8 kv = *(const half8*)(qkv + (size_t)g * NQKV + HID + h * HD + dblk * 8);
    *(half8*)(kimg + ibase + ((j * 256 + 16 * dblk) ^ ((j & 7) << 4))) = kv;
    half8 vv = *(const half8*)(qkv + (size_t)g * NQKV + 2 * HID + h * HD + dblk * 8);
    *(half8*)(&Vs[j * 136 + dblk * 8]) = vv;
  }
  __syncthreads();
#pragma unroll
  for (int it = 0; it < 4; ++it) {
    int idx = tid + 256 * it;           // (jblk, d): 8 x 128
    int jblk = idx >> 7, d = idx & 127;
    half8 o;
#pragma unroll
    for (int q = 0; q < 8; ++q) o[q] = Vs[(jblk * 8 + q) * 136 + d];
    *(half8*)(vtimg + ibase + ((d * 128 + 16 * jblk) ^ ((d & 7) << 4))) = o;
  }
}

// ---------- f16 MFMA flash attention: swapped QK^T, in-register softmax/P ----------
// 512 threads = 8 waves, QBLK=128 (16 rows/wave, row q = lane&15), KV tiles of 64.
// LDS: 2 x (K 16KB + Vt 16KB) = 64KB. P never touches LDS.
__global__ __launch_bounds__(512, 4)
void k_attn3(const _Float16* __restrict__ qkv, const char* __restrict__ kimg,
             const char* __restrict__ vtimg, const int* __restrict__ hmap,
             _Float16* __restrict__ att)
{
  extern __shared__ __align__(16) char lds[];
  const int tid = threadIdx.x;
  const int w = tid >> 6, lane = tid & 63;
  const int l15 = lane & 15, l4 = lane >> 4;
  const int work = (blockIdx.x & 7) * 64 + (blockIdx.x >> 3);  // XCD-chunked
  const int h  = work >> 5;
  const int q0 = (work & 31) * QBLK;

  // Q fragments (B operand: col = lane&15 = q-row, k = l4*8+r), prescaled
  half8 qf[4];
  {
    const int qrow = q0 + w * 16 + l15;
    const _Float16* qb = qkv + (size_t)qrow * NQKV + h * HD + l4 * 8;
    const _Float16 qs = (_Float16)QSCALE;
#pragma unroll
    for (int ks = 0; ks < 4; ++ks) {
      half8 v = *(const half8*)(qb + 32 * ks);
#pragma unroll
      for (int q = 0; q < 8; ++q) v[q] *= qs;
      qf[ks] = v;
    }
  }

  const char* kbase = kimg  + (size_t)h * NT * 16384;
  const char* vbase = vtimg + (size_t)h * NT * 16384;

  f32x4 acc[8];
#pragma unroll
  for (int dt = 0; dt < 8; ++dt) acc[dt] = (f32x4){0.f, 0.f, 0.f, 0.f};
  float m = -1e30f, l = 0.f;

  // P redistribution source lanes (same q=l15, other l4 groups)
  const int src0 = l15 + 16 * (2 * (l4 & 1));
  const int src1 = src0 + 16;
  const bool hi = (l4 >> 1) != 0;

#define STAGE(buf, t)                                                          \
  do {                                                                         \
    const char* ks_ = kbase + (size_t)(t) * 16384;                             \
    const char* vs_ = vbase + (size_t)(t) * 16384;                             \
    char* d_ = lds + (buf) * 32768;                                            \
    gload16(ks_ + w * 1024 + lane * 16,          d_ + w * 1024);               \
    gload16(ks_ + (8 + w) * 1024 + lane * 16,    d_ + (8 + w) * 1024);         \
    gload16(vs_ + w * 1024 + lane * 16,          d_ + 16384 + w * 1024);       \
    gload16(vs_ + (8 + w) * 1024 + lane * 16,    d_ + 16384 + (8 + w) * 1024); \
  } while (0)

  STAGE(0, 0);
  asm volatile("s_waitcnt vmcnt(0)");
  __syncthreads();

  int cur = 0;
  for (int t = 0; t < NT; ++t) {
    if (t + 1 < NT) STAGE(cur ^ 1, t + 1);
    const char* kl = lds + cur * 32768;
    const char* vl = kl + 16384;

    // QK^T swapped: S^T = K * Q -> lane holds S[q=l15][j=jt*16+4*l4+e]
    f32x4 s[4];
    __builtin_amdgcn_s_setprio(1);
#pragma unroll
    for (int jt = 0; jt < 4; ++jt) {
      f32x4 ss = (f32x4){0.f, 0.f, 0.f, 0.f};
#pragma unroll
      for (int ks = 0; ks < 4; ++ks) {
        int j = jt * 16 + l15;
        half8 kf = *(const half8*)(kl + ((j * 256 + 64 * ks + 16 * l4) ^ ((j & 7) << 4)));
        ss = __builtin_amdgcn_mfma_f32_16x16x32_f16(kf, qf[ks], ss, 0, 0, 0);
      }
      s[jt] = ss;
    }
    __builtin_amdgcn_s_setprio(0);

    // per-row max: in-lane over 16 + reduce across l4 groups
    float vmax = -1e30f;
#pragma unroll
    for (int jt = 0; jt < 4; ++jt) {
      vmax = fmaxf(vmax, fmaxf(fmaxf(s[jt][0], s[jt][1]), fmaxf(s[jt][2], s[jt][3])));
    }
    vmax = fmaxf(vmax, __shfl_xor(vmax, 16));
    vmax = fmaxf(vmax, __shfl_xor(vmax, 32));

    // defer-max (log2 domain, THR=8 -> P <= 256 fits f16)
    if (__any(vmax > m + 8.f)) {
      float mn = fmaxf(m, vmax);
      float corr = exp2f(m - mn);
      l *= corr;
      m = mn;
#pragma unroll
      for (int dt = 0; dt < 8; ++dt) {
        acc[dt][0] *= corr; acc[dt][1] *= corr;
        acc[dt][2] *= corr; acc[dt][3] *= corr;
      }
    }

    // P = exp2(S - m), packed to f16 pairs in-register
    unsigned pk[4][2];
    float psum = 0.f;
#pragma unroll
    for (int jt = 0; jt < 4; ++jt) {
      float p0 = exp2f(s[jt][0] - m);
      float p1 = exp2f(s[jt][1] - m);
      float p2 = exp2f(s[jt][2] - m);
      float p3 = exp2f(s[jt][3] - m);
      psum += (p0 + p1) + (p2 + p3);
      pk[jt][0] = pkrtz(p0, p1);
      pk[jt][1] = pkrtz(p2, p3);
    }
    psum += __shfl_xor(psum, 16);
    psum += __shfl_xor(psum, 32);
    l += psum;

    // PV swapped: acc[d][q] += Vt * P^T.  B-frag r: j = ks2*32 + l4*8 + r,
    // value = pk[ks2*2+(l4>>1)][...] redistributed from lane l15+16*group.
#pragma unroll
    for (int ks2 = 0; ks2 < 2; ++ks2) {
      int a0 = (int)pk[2 * ks2][0], a1 = (int)pk[2 * ks2][1];
      int b0 = (int)pk[2 * ks2 + 1][0], b1 = (int)pk[2 * ks2 + 1][1];
      int d0A = __shfl(a0, src0), d0B = __shfl(b0, src0);
      int d1A = __shfl(a1, src0), d1B = __shfl(b1, src0);
      int d2A = __shfl(a0, src1), d2B = __shfl(b0, src1);
      int d3A = __shfl(a1, src1), d3B = __shfl(b1, src1);
      union { int u[4]; half8 hv; } pf;
      pf.u[0] = hi ? d0B : d0A;
      pf.u[1] = hi ? d1B : d1A;
      pf.u[2] = hi ? d2B : d2A;
      pf.u[3] = hi ? d3B : d3A;
      __builtin_amdgcn_s_setprio(1);
#pragma unroll
      for (int dt = 0; dt < 8; ++dt) {
        int d = dt * 16 + l15;
        half8 vf = *(const half8*)(vl + ((d * 128 + 64 * ks2 + 16 * l4) ^ ((d & 7) << 4)));
        acc[dt] = __builtin_amdgcn_mfma_f32_16x16x32_f16(vf, pf.hv, acc[dt], 0, 0, 0);
      }
      __builtin_amdgcn_s_setprio(0);
    }

    asm volatile("s_waitcnt vmcnt(0)");
    __syncthreads();
    cur ^= 1;
  }
#undef STAGE

  // epilogue: lane owns out[q=l15][d = dt*16+4*l4+0..3]; scatter row by hmap
  const float rl = 1.0f / l;
  const int row = q0 + w * 16 + l15;
  const int srow = hmap[row];
  _Float16* ob = att + (size_t)srow * HID + h * HD;
#pragma unroll
  for (int dt = 0; dt < 8; ++dt) {
    half4 o;
    o[0] = (_Float16)(acc[dt][0] * rl);
    o[1] = (_Float16)(acc[dt][1] * rl);
    o[2] = (_Float16)(acc[dt][2] * rl);
    o[3] = (_Float16)(acc[dt][3] * rl);
    *(half4*)(ob + dt * 16 + 4 * l4) = o;
  }
}

extern "C" void kernel_launch(void* const* d_in, const int* in_sizes, int n_in,
                              void* d_out, int out_size, void* d_ws, size_t ws_size,
                              hipStream_t stream)
{
  const float* x     = (const float*)d_in[0];
  const float* w_qkv = (const float*)d_in[1];
  const float* w_out = (const float*)d_in[2];
  const int*   hmap  = (const int*)d_in[3];
  float* out = (float*)d_out;

  char* ws = (char*)d_ws;
  int* gidx = (int*)ws;                                          ws += 8192;
  _Float16* x16    = (_Float16*)ws;  // aliased with att16 (x16 dead after GEMM1)
  _Float16* att16  = (_Float16*)ws;                              ws += (size_t)S_LEN * HID * 2;
  _Float16* wqkv16 = (_Float16*)ws;                              ws += (size_t)NQKV * HID * 2;
  _Float16* wout16 = (_Float16*)ws;                              ws += (size_t)HID * HID * 2;
  _Float16* qkv16  = (_Float16*)ws;                              ws += (size_t)S_LEN * NQKV * 2;
  char* kimg  = ws;                                              ws += (size_t)NH * NT * 16384;
  char* vtimg = ws;

  k_build_idx<<<8, 256, 0, stream>>>(hmap, gidx);

  k_cvt_f16<<<(S_LEN * HID / 8 + 255) / 256, 256, 0, stream>>>(x, x16, S_LEN * HID / 8);
  k_cvt_f16<<<(NQKV * HID / 8 + 255) / 256, 256, 0, stream>>>(w_qkv, wqkv16, NQKV * HID / 8);
  k_cvt_f16<<<(HID * HID / 8 + 255) / 256, 256, 0, stream>>>(w_out, wout16, HID * HID / 8);

  dim3 g1(NQKV / 128, S_LEN / 128);
  k_gemm_f16<false><<<g1, 256, 0, stream>>>(x16, wqkv16, qkv16, S_LEN, NQKV, HID);

  k_prep<<<NH * NT, 256, 0, stream>>>(qkv16, gidx, kimg, vtimg);

  k_attn3<<<NH * (S_LEN / QBLK), 512, 65536, stream>>>(qkv16, kimg, vtimg, hmap, att16);

  dim3 g3(HID / 128, S_LEN / 128);
  k_gemm_f16<true><<<g3, 256, 0, stream>>>(att16, wout16, out, S_LEN, HID, HID);
}

// Round 7
// 262.479 us; speedup vs baseline: 12.1649x; 1.3002x over previous
//
#include <hip/hip_runtime.h>
#include <math.h>

#define S_LEN 4096
#define HID   2048
#define NH    16
#define HD    128
#define NKV   2048
#define KT    64
#define QBLK  128
#define NT    (NKV / KT)
// (1/sqrt(128)) * log2(e) -- folded into Q so QK^T lands in exp2 domain
#define QSCALE 0.12754103668587426f

typedef __attribute__((ext_vector_type(8))) _Float16 half8;
typedef __attribute__((ext_vector_type(4))) _Float16 half4;
typedef __attribute__((ext_vector_type(2))) __fp16 fp16x2;
typedef __attribute__((ext_vector_type(4))) float f32x4;

#define GLB_AS __attribute__((address_space(1)))
#define LDS_AS __attribute__((address_space(3)))

__device__ __forceinline__ void gload16(const void* g, void* l) {
  __builtin_amdgcn_global_load_lds((GLB_AS const void*)g, (LDS_AS void*)l, 16, 0, 0);
}

__device__ __forceinline__ unsigned pkrtz(float a, float b) {
  union { fp16x2 h; unsigned u; } cv;
  cv.h = __builtin_amdgcn_cvt_pkrtz(a, b);
  return cv.u;
}

// ---------- index build ----------
__global__ void k_build_idx(const int* __restrict__ hmap, int* __restrict__ gidx) {
  int i = blockIdx.x * 256 + threadIdx.x;
  if (i < NKV) gidx[i] = hmap[2 * i];
}

// ---------- fp32 -> fp16 conversion ----------
__global__ void k_cvt_f16(const float* __restrict__ src, _Float16* __restrict__ dst, int n8) {
  int i = blockIdx.x * 256 + threadIdx.x;
  if (i < n8) {
    float4 a = ((const float4*)src)[2 * i];
    float4 b = ((const float4*)src)[2 * i + 1];
    half8 h;
    h[0] = (_Float16)a.x; h[1] = (_Float16)a.y; h[2] = (_Float16)a.z; h[3] = (_Float16)a.w;
    h[4] = (_Float16)b.x; h[5] = (_Float16)b.y; h[6] = (_Float16)b.z; h[7] = (_Float16)b.w;
    ((half8*)dst)[i] = h;
  }
}

// ---------- fp16 MFMA NT GEMM, BK=64, swizzled LDS, staged-under-MFMA ----------
// 128x128 tile, 256 threads = 4 waves (2x2). LDS [128][64]f16 per matrix,
// phys slot = (logical k-slot) ^ (row&7); linear gload_lds dest + pre-swizzled
// global source. Optional A-row gather (arow).
template<bool OUT_F32>
__global__ __launch_bounds__(256)
void k_gemm2(const _Float16* __restrict__ A, const _Float16* __restrict__ B,
             void* __restrict__ Cv, int M, int N, int K,
             const int* __restrict__ arow)
{
  __shared__ __align__(16) char Asl[16384];
  __shared__ __align__(16) char Bsl[16384];
  const int tid = threadIdx.x;
  const int w = tid >> 6, lane = tid & 63;
  const int l15 = lane & 15, l4 = lane >> 4;
  const int m0 = blockIdx.y * 128, n0 = blockIdx.x * 128;
  const int wr = w >> 1, wc = w & 1;

  // staging: wave w owns granules 4w+q (q=0..3); granule = 8 rows x 128B.
  // lane -> row-in-granule = lane>>3, phys slot = lane&7,
  // logical slot = (lane&7) ^ (lane>>3)  -> global k-offset
  const int srow  = lane >> 3;
  const int kso   = ((lane & 7) ^ srow) * 8;   // f16 elements
  const _Float16* Ap[4];
  const _Float16* Bp[4];
#pragma unroll
  for (int q = 0; q < 4; ++q) {
    int arel = m0 + 32 * w + 8 * q + srow;
    int ra = arow ? arow[arel] : arel;
    Ap[q] = A + (size_t)ra * K + kso;
    Bp[q] = B + (size_t)(n0 + 32 * w + 8 * q + srow) * K + kso;
  }

  f32x4 acc[4][4];
#pragma unroll
  for (int i = 0; i < 4; ++i)
#pragma unroll
    for (int j = 0; j < 4; ++j) acc[i][j] = (f32x4){0.f, 0.f, 0.f, 0.f};

#define STAGE_T(k0)                                                  \
  do {                                                               \
    _Pragma("unroll")                                                \
    for (int q = 0; q < 4; ++q) {                                    \
      gload16(Ap[q] + (k0), Asl + (4 * w + q) * 1024 + lane * 16);   \
      gload16(Bp[q] + (k0), Bsl + (4 * w + q) * 1024 + lane * 16);   \
    }                                                                \
  } while (0)

  STAGE_T(0);
  __syncthreads();

  const int nt = K >> 6;
  for (int t = 0; t < nt; ++t) {
    // read all fragments (swizzled addresses)
    half8 af[4][2], bf[4][2];
#pragma unroll
    for (int mi = 0; mi < 4; ++mi) {
      int row = wr * 64 + mi * 16 + l15;
#pragma unroll
      for (int ks = 0; ks < 2; ++ks)
        af[mi][ks] = *(const half8*)(Asl + row * 128 + (((ks * 4 + l4) ^ (row & 7)) * 16));
    }
#pragma unroll
    for (int ni = 0; ni < 4; ++ni) {
      int row = wc * 64 + ni * 16 + l15;
#pragma unroll
      for (int ks = 0; ks < 2; ++ks)
        bf[ni][ks] = *(const half8*)(Bsl + row * 128 + (((ks * 4 + l4) ^ (row & 7)) * 16));
    }
    __syncthreads();                 // all waves done reading LDS
    if (t + 1 < nt) STAGE_T((t + 1) * 64);   // overwrite while MFMAs run
    __builtin_amdgcn_s_setprio(1);
#pragma unroll
    for (int mi = 0; mi < 4; ++mi)
#pragma unroll
      for (int ni = 0; ni < 4; ++ni)
#pragma unroll
        for (int ks = 0; ks < 2; ++ks)
          acc[mi][ni] = __builtin_amdgcn_mfma_f32_16x16x32_f16(af[mi][ks], bf[ni][ks], acc[mi][ni], 0, 0, 0);
    __builtin_amdgcn_s_setprio(0);
    __syncthreads();                 // staging complete (drains vmcnt)
  }
#undef STAGE_T

  const int rbase = m0 + wr * 64 + l4 * 4;
  const int cbase = n0 + wc * 64 + l15;
#pragma unroll
  for (int mi = 0; mi < 4; ++mi)
#pragma unroll
    for (int ni = 0; ni < 4; ++ni)
#pragma unroll
      for (int e = 0; e < 4; ++e) {
        size_t idx = (size_t)(rbase + mi * 16 + e) * N + cbase + ni * 16;
        if (OUT_F32) ((float*)Cv)[idx] = acc[mi][ni][e];
        else ((_Float16*)Cv)[idx] = (_Float16)acc[mi][ni][e];
      }
}

// ---------- prep: pre-swizzled K / Vt LDS images from compact kv16 ----------
// kv16: [2048 gathered rows][4096] (cols 0..2047 = K heads, 2048.. = V heads)
__global__ __launch_bounds__(256)
void k_prep(const _Float16* __restrict__ kv, char* __restrict__ kimg,
            char* __restrict__ vtimg)
{
  __shared__ _Float16 Vs[64 * 136];
  const int tid = threadIdx.x;
  const int h = blockIdx.x >> 5;
  const int t = blockIdx.x & 31;
  const size_t ibase = (size_t)blockIdx.x * 16384;

#pragma unroll
  for (int it = 0; it < 4; ++it) {
    int idx = tid + 256 * it;           // (j, dblk): 64 x 16
    int j = idx >> 4, dblk = idx & 15;
    const _Float16* rb = kv + (size_t)(t * KT + j) * (2 * HID) + h * HD + dblk * 8;
    half8 kvv = *(const half8*)rb;
    *(half8*)(kimg + ibase + ((j * 256 + 16 * dblk) ^ ((j & 7) << 4))) = kvv;
    half8 vv = *(const half8*)(rb + HID);
    *(half8*)(&Vs[j * 136 + dblk * 8]) = vv;
  }
  __syncthreads();
#pragma unroll
  for (int it = 0; it < 4; ++it) {
    int idx = tid + 256 * it;           // (jblk, d): 8 x 128
    int jblk = idx >> 7, d = idx & 127;
    half8 o;
#pragma unroll
    for (int q = 0; q < 8; ++q) o[q] = Vs[(jblk * 8 + q) * 136 + d];
    *(half8*)(vtimg + ibase + ((d * 128 + 16 * jblk) ^ ((d & 7) << 4))) = o;
  }
}

// ---------- f16 MFMA flash attention: swapped QK^T, in-register softmax/P ----------
__global__ __launch_bounds__(512, 4)
void k_attn3(const _Float16* __restrict__ qmat, const char* __restrict__ kimg,
             const char* __restrict__ vtimg, const int* __restrict__ hmap,
             _Float16* __restrict__ att)
{
  extern __shared__ __align__(16) char lds[];
  const int tid = threadIdx.x;
  const int w = tid >> 6, lane = tid & 63;
  const int l15 = lane & 15, l4 = lane >> 4;
  const int work = (blockIdx.x & 7) * 64 + (blockIdx.x >> 3);  // XCD-chunked
  const int h  = work >> 5;
  const int q0 = (work & 31) * QBLK;

  half8 qf[4];
  {
    const int qrow = q0 + w * 16 + l15;
    const _Float16* qb = qmat + (size_t)qrow * HID + h * HD + l4 * 8;
    const _Float16 qs = (_Float16)QSCALE;
#pragma unroll
    for (int ks = 0; ks < 4; ++ks) {
      half8 v = *(const half8*)(qb + 32 * ks);
#pragma unroll
      for (int q = 0; q < 8; ++q) v[q] *= qs;
      qf[ks] = v;
    }
  }

  const char* kbase = kimg  + (size_t)h * NT * 16384;
  const char* vbase = vtimg + (size_t)h * NT * 16384;

  f32x4 acc[8];
#pragma unroll
  for (int dt = 0; dt < 8; ++dt) acc[dt] = (f32x4){0.f, 0.f, 0.f, 0.f};
  float m = -1e30f, l = 0.f;

  const int src0 = l15 + 16 * (2 * (l4 & 1));
  const int src1 = src0 + 16;
  const bool hi = (l4 >> 1) != 0;

#define STAGE(buf, t)                                                          \
  do {                                                                         \
    const char* ks_ = kbase + (size_t)(t) * 16384;                             \
    const char* vs_ = vbase + (size_t)(t) * 16384;                             \
    char* d_ = lds + (buf) * 32768;                                            \
    gload16(ks_ + w * 1024 + lane * 16,          d_ + w * 1024);               \
    gload16(ks_ + (8 + w) * 1024 + lane * 16,    d_ + (8 + w) * 1024);         \
    gload16(vs_ + w * 1024 + lane * 16,          d_ + 16384 + w * 1024);       \
    gload16(vs_ + (8 + w) * 1024 + lane * 16,    d_ + 16384 + (8 + w) * 1024); \
  } while (0)

  STAGE(0, 0);
  asm volatile("s_waitcnt vmcnt(0)");
  __syncthreads();

  int cur = 0;
  for (int t = 0; t < NT; ++t) {
    if (t + 1 < NT) STAGE(cur ^ 1, t + 1);
    const char* kl = lds + cur * 32768;
    const char* vl = kl + 16384;

    f32x4 s[4];
    __builtin_amdgcn_s_setprio(1);
#pragma unroll
    for (int jt = 0; jt < 4; ++jt) {
      f32x4 ss = (f32x4){0.f, 0.f, 0.f, 0.f};
#pragma unroll
      for (int ks = 0; ks < 4; ++ks) {
        int j = jt * 16 + l15;
        half8 kf = *(const half8*)(kl + ((j * 256 + 64 * ks + 16 * l4) ^ ((j & 7) << 4)));
        ss = __builtin_amdgcn_mfma_f32_16x16x32_f16(kf, qf[ks], ss, 0, 0, 0);
      }
      s[jt] = ss;
    }
    __builtin_amdgcn_s_setprio(0);

    float vmax = -1e30f;
#pragma unroll
    for (int jt = 0; jt < 4; ++jt)
      vmax = fmaxf(vmax, fmaxf(fmaxf(s[jt][0], s[jt][1]), fmaxf(s[jt][2], s[jt][3])));
    vmax = fmaxf(vmax, __shfl_xor(vmax, 16));
    vmax = fmaxf(vmax, __shfl_xor(vmax, 32));

    if (__any(vmax > m + 8.f)) {
      float mn = fmaxf(m, vmax);
      float corr = exp2f(m - mn);
      l *= corr;
      m = mn;
#pragma unroll
      for (int dt = 0; dt < 8; ++dt) {
        acc[dt][0] *= corr; acc[dt][1] *= corr;
        acc[dt][2] *= corr; acc[dt][3] *= corr;
      }
    }

    unsigned pk[4][2];
    float psum = 0.f;
#pragma unroll
    for (int jt = 0; jt < 4; ++jt) {
      float p0 = exp2f(s[jt][0] - m);
      float p1 = exp2f(s[jt][1] - m);
      float p2 = exp2f(s[jt][2] - m);
      float p3 = exp2f(s[jt][3] - m);
      psum += (p0 + p1) + (p2 + p3);
      pk[jt][0] = pkrtz(p0, p1);
      pk[jt][1] = pkrtz(p2, p3);
    }
    psum += __shfl_xor(psum, 16);
    psum += __shfl_xor(psum, 32);
    l += psum;

#pragma unroll
    for (int ks2 = 0; ks2 < 2; ++ks2) {
      int a0 = (int)pk[2 * ks2][0], a1 = (int)pk[2 * ks2][1];
      int b0 = (int)pk[2 * ks2 + 1][0], b1 = (int)pk[2 * ks2 + 1][1];
      int d0A = __shfl(a0, src0), d0B = __shfl(b0, src0);
      int d1A = __shfl(a1, src0), d1B = __shfl(b1, src0);
      int d2A = __shfl(a0, src1), d2B = __shfl(b0, src1);
      int d3A = __shfl(a1, src1), d3B = __shfl(b1, src1);
      union { int u[4]; half8 hv; } pf;
      pf.u[0] = hi ? d0B : d0A;
      pf.u[1] = hi ? d1B : d1A;
      pf.u[2] = hi ? d2B : d2A;
      pf.u[3] = hi ? d3B : d3A;
      __builtin_amdgcn_s_setprio(1);
#pragma unroll
      for (int dt = 0; dt < 8; ++dt) {
        int d = dt * 16 + l15;
        half8 vf = *(const half8*)(vl + ((d * 128 + 64 * ks2 + 16 * l4) ^ ((d & 7) << 4)));
        acc[dt] = __builtin_amdgcn_mfma_f32_16x16x32_f16(vf, pf.hv, acc[dt], 0, 0, 0);
      }
      __builtin_amdgcn_s_setprio(0);
    }

    asm volatile("s_waitcnt vmcnt(0)");
    __syncthreads();
    cur ^= 1;
  }
#undef STAGE

  const float rl = 1.0f / l;
  const int row = q0 + w * 16 + l15;
  const int srow = hmap[row];
  _Float16* ob = att + (size_t)srow * HID + h * HD;
#pragma unroll
  for (int dt = 0; dt < 8; ++dt) {
    half4 o;
    o[0] = (_Float16)(acc[dt][0] * rl);
    o[1] = (_Float16)(acc[dt][1] * rl);
    o[2] = (_Float16)(acc[dt][2] * rl);
    o[3] = (_Float16)(acc[dt][3] * rl);
    *(half4*)(ob + dt * 16 + 4 * l4) = o;
  }
}

extern "C" void kernel_launch(void* const* d_in, const int* in_sizes, int n_in,
                              void* d_out, int out_size, void* d_ws, size_t ws_size,
                              hipStream_t stream)
{
  const float* x     = (const float*)d_in[0];
  const float* w_qkv = (const float*)d_in[1];
  const float* w_out = (const float*)d_in[2];
  const int*   hmap  = (const int*)d_in[3];
  float* out = (float*)d_out;

  char* ws = (char*)d_ws;
  int* gidx = (int*)ws;                                          ws += 8192;
  _Float16* x16    = (_Float16*)ws;  // aliased with att16 (x16 dead after GEMMs 1a/1b)
  _Float16* att16  = (_Float16*)ws;                              ws += (size_t)S_LEN * HID * 2;
  _Float16* wqkv16 = (_Float16*)ws;                              ws += (size_t)3 * HID * HID * 2;
  _Float16* wout16 = (_Float16*)ws;                              ws += (size_t)HID * HID * 2;
  _Float16* q16    = (_Float16*)ws;                              ws += (size_t)S_LEN * HID * 2;
  _Float16* kv16   = (_Float16*)ws;                              ws += (size_t)NKV * 2 * HID * 2;
  char* kimg  = ws;                                              ws += (size_t)NH * NT * 16384;
  char* vtimg = ws;

  k_build_idx<<<8, 256, 0, stream>>>(hmap, gidx);

  k_cvt_f16<<<(S_LEN * HID / 8 + 255) / 256, 256, 0, stream>>>(x, x16, S_LEN * HID / 8);
  k_cvt_f16<<<(3 * HID * HID / 8 + 255) / 256, 256, 0, stream>>>(w_qkv, wqkv16, 3 * HID * HID / 8);
  k_cvt_f16<<<(HID * HID / 8 + 255) / 256, 256, 0, stream>>>(w_out, wout16, HID * HID / 8);

  // Q = x @ wq^T  (4096 x 2048)
  dim3 gq(HID / 128, S_LEN / 128);
  k_gemm2<false><<<gq, 256, 0, stream>>>(x16, wqkv16, q16, S_LEN, HID, HID, nullptr);
  // KV = x[gidx] @ wkv^T  (2048 x 4096), compact gathered rows
  dim3 gkv(2 * HID / 128, NKV / 128);
  k_gemm2<false><<<gkv, 256, 0, stream>>>(x16, wqkv16 + (size_t)HID * HID, kv16,
                                          NKV, 2 * HID, HID, gidx);

  k_prep<<<NH * NT, 256, 0, stream>>>(kv16, kimg, vtimg);

  k_attn3<<<NH * (S_LEN / QBLK), 512, 65536, stream>>>(q16, kimg, vtimg, hmap, att16);

  // out = att @ w_out^T  (4096 x 2048, fp32)
  dim3 go(HID / 128, S_LEN / 128);
  k_gemm2<true><<<go, 256, 0, stream>>>(att16, wout16, out, S_LEN, HID, HID, nullptr);
}

// Round 8
// 244.340 us; speedup vs baseline: 13.0681x; 1.0742x over previous
//
#include <hip/hip_runtime.h>
#include <math.h>

#define S_LEN 4096
#define HID   2048
#define NH    16
#define HD    128
#define NKV   2048
#define KT    64
#define QBLK  256
#define NT    (NKV / KT)
// (1/sqrt(128)) * log2(e) -- folded into Q so QK^T lands in exp2 domain
#define QSCALE 0.12754103668587426f

typedef __attribute__((ext_vector_type(8))) _Float16 half8;
typedef __attribute__((ext_vector_type(4))) _Float16 half4;
typedef __attribute__((ext_vector_type(2))) __fp16 fp16x2;
typedef __attribute__((ext_vector_type(4))) float f32x4;
typedef __attribute__((ext_vector_type(16))) float f32x16;

#define GLB_AS __attribute__((address_space(1)))
#define LDS_AS __attribute__((address_space(3)))

__device__ __forceinline__ void gload16(const void* g, void* l) {
  __builtin_amdgcn_global_load_lds((GLB_AS const void*)g, (LDS_AS void*)l, 16, 0, 0);
}

__device__ __forceinline__ unsigned pkrtz(float a, float b) {
  union { fp16x2 h; unsigned u; } cv;
  cv.h = __builtin_amdgcn_cvt_pkrtz(a, b);
  return cv.u;
}

// ---------- index build ----------
__global__ void k_build_idx(const int* __restrict__ hmap, int* __restrict__ gidx) {
  int i = blockIdx.x * 256 + threadIdx.x;
  if (i < NKV) gidx[i] = hmap[2 * i];
}

// ---------- fp32 -> fp16 conversion ----------
__global__ void k_cvt_f16(const float* __restrict__ src, _Float16* __restrict__ dst, int n8) {
  int i = blockIdx.x * 256 + threadIdx.x;
  if (i < n8) {
    float4 a = ((const float4*)src)[2 * i];
    float4 b = ((const float4*)src)[2 * i + 1];
    half8 h;
    h[0] = (_Float16)a.x; h[1] = (_Float16)a.y; h[2] = (_Float16)a.z; h[3] = (_Float16)a.w;
    h[4] = (_Float16)b.x; h[5] = (_Float16)b.y; h[6] = (_Float16)b.z; h[7] = (_Float16)b.w;
    ((half8*)dst)[i] = h;
  }
}

// ---------- fp16 MFMA NT GEMM, BK=64, swizzled LDS, staged-under-MFMA ----------
template<bool OUT_F32>
__global__ __launch_bounds__(256)
void k_gemm2(const _Float16* __restrict__ A, const _Float16* __restrict__ B,
             void* __restrict__ Cv, int M, int N, int K,
             const int* __restrict__ arow)
{
  __shared__ __align__(16) char Asl[16384];
  __shared__ __align__(16) char Bsl[16384];
  const int tid = threadIdx.x;
  const int w = tid >> 6, lane = tid & 63;
  const int l15 = lane & 15, l4 = lane >> 4;
  const int m0 = blockIdx.y * 128, n0 = blockIdx.x * 128;
  const int wr = w >> 1, wc = w & 1;

  const int srow  = lane >> 3;
  const int kso   = ((lane & 7) ^ srow) * 8;   // f16 elements
  const _Float16* Ap[4];
  const _Float16* Bp[4];
#pragma unroll
  for (int q = 0; q < 4; ++q) {
    int arel = m0 + 32 * w + 8 * q + srow;
    int ra = arow ? arow[arel] : arel;
    Ap[q] = A + (size_t)ra * K + kso;
    Bp[q] = B + (size_t)(n0 + 32 * w + 8 * q + srow) * K + kso;
  }

  f32x4 acc[4][4];
#pragma unroll
  for (int i = 0; i < 4; ++i)
#pragma unroll
    for (int j = 0; j < 4; ++j) acc[i][j] = (f32x4){0.f, 0.f, 0.f, 0.f};

#define STAGE_T(k0)                                                  \
  do {                                                               \
    _Pragma("unroll")                                                \
    for (int q = 0; q < 4; ++q) {                                    \
      gload16(Ap[q] + (k0), Asl + (4 * w + q) * 1024 + lane * 16);   \
      gload16(Bp[q] + (k0), Bsl + (4 * w + q) * 1024 + lane * 16);   \
    }                                                                \
  } while (0)

  STAGE_T(0);
  __syncthreads();

  const int nt = K >> 6;
  for (int t = 0; t < nt; ++t) {
    half8 af[4][2], bf[4][2];
#pragma unroll
    for (int mi = 0; mi < 4; ++mi) {
      int row = wr * 64 + mi * 16 + l15;
#pragma unroll
      for (int ks = 0; ks < 2; ++ks)
        af[mi][ks] = *(const half8*)(Asl + row * 128 + (((ks * 4 + l4) ^ (row & 7)) * 16));
    }
#pragma unroll
    for (int ni = 0; ni < 4; ++ni) {
      int row = wc * 64 + ni * 16 + l15;
#pragma unroll
      for (int ks = 0; ks < 2; ++ks)
        bf[ni][ks] = *(const half8*)(Bsl + row * 128 + (((ks * 4 + l4) ^ (row & 7)) * 16));
    }
    __syncthreads();
    if (t + 1 < nt) STAGE_T((t + 1) * 64);
    __builtin_amdgcn_s_setprio(1);
#pragma unroll
    for (int mi = 0; mi < 4; ++mi)
#pragma unroll
      for (int ni = 0; ni < 4; ++ni)
#pragma unroll
        for (int ks = 0; ks < 2; ++ks)
          acc[mi][ni] = __builtin_amdgcn_mfma_f32_16x16x32_f16(af[mi][ks], bf[ni][ks], acc[mi][ni], 0, 0, 0);
    __builtin_amdgcn_s_setprio(0);
    __syncthreads();
  }
#undef STAGE_T

  const int rbase = m0 + wr * 64 + l4 * 4;
  const int cbase = n0 + wc * 64 + l15;
#pragma unroll
  for (int mi = 0; mi < 4; ++mi)
#pragma unroll
    for (int ni = 0; ni < 4; ++ni)
#pragma unroll
      for (int e = 0; e < 4; ++e) {
        size_t idx = (size_t)(rbase + mi * 16 + e) * N + cbase + ni * 16;
        if (OUT_F32) ((float*)Cv)[idx] = acc[mi][ni][e];
        else ((_Float16*)Cv)[idx] = (_Float16)acc[mi][ni][e];
      }
}

// ---------- prep: pre-swizzled K / Vt LDS images from compact kv16 ----------
__global__ __launch_bounds__(256)
void k_prep(const _Float16* __restrict__ kv, char* __restrict__ kimg,
            char* __restrict__ vtimg)
{
  __shared__ _Float16 Vs[64 * 136];
  const int tid = threadIdx.x;
  const int h = blockIdx.x >> 5;
  const int t = blockIdx.x & 31;
  const size_t ibase = (size_t)blockIdx.x * 16384;

#pragma unroll
  for (int it = 0; it < 4; ++it) {
    int idx = tid + 256 * it;           // (j, dblk): 64 x 16
    int j = idx >> 4, dblk = idx & 15;
    const _Float16* rb = kv + (size_t)(t * KT + j) * (2 * HID) + h * HD + dblk * 8;
    half8 kvv = *(const half8*)rb;
    *(half8*)(kimg + ibase + ((j * 256 + 16 * dblk) ^ ((j & 7) << 4))) = kvv;
    half8 vv = *(const half8*)(rb + HID);
    *(half8*)(&Vs[j * 136 + dblk * 8]) = vv;
  }
  __syncthreads();
#pragma unroll
  for (int it = 0; it < 4; ++it) {
    int idx = tid + 256 * it;           // (jblk, d): 8 x 128
    int jblk = idx >> 7, d = idx & 127;
    half8 o;
#pragma unroll
    for (int q = 0; q < 8; ++q) o[q] = Vs[(jblk * 8 + q) * 136 + d];
    *(half8*)(vtimg + ibase + ((d * 128 + 16 * jblk) ^ ((d & 7) << 4))) = o;
  }
}

// ---------- 32x32 MFMA flash attention: swapped ops, in-register softmax/P ----------
// 512 threads = 8 waves; wave owns 32 q rows (q = l&31); KV tiles of 64.
// grid = 256 blocks (1/CU). LDS 2 x (K 16KB + Vt 16KB) = 64KB.
__global__ __launch_bounds__(512, 2)
void k_attn4(const _Float16* __restrict__ qmat, const char* __restrict__ kimg,
             const char* __restrict__ vtimg, const int* __restrict__ hmap,
             _Float16* __restrict__ att)
{
  extern __shared__ __align__(16) char lds[];
  const int tid = threadIdx.x;
  const int w = tid >> 6, lane = tid & 63;
  const int l31 = lane & 31;
  const bool hi = (lane >> 5) != 0;
  const int hib = hi ? 1 : 0;
  const int work = (blockIdx.x & 7) * 32 + (blockIdx.x >> 3);  // XCD-chunked, bijective
  const int h  = work >> 4;
  const int q0 = (work & 15) * QBLK;

  // Q fragments (B operand): qf[dk]: d = dk*16 + hi*8 + e, col q = l31; prescaled
  half8 qf[8];
  {
    const int qrow = q0 + w * 32 + l31;
    const _Float16* qb = qmat + (size_t)qrow * HID + h * HD + hib * 8;
    const _Float16 qs = (_Float16)QSCALE;
#pragma unroll
    for (int dk = 0; dk < 8; ++dk) {
      half8 v = *(const half8*)(qb + 16 * dk);
#pragma unroll
      for (int q = 0; q < 8; ++q) v[q] *= qs;
      qf[dk] = v;
    }
  }

  half8 ones;
#pragma unroll
  for (int q = 0; q < 8; ++q) ones[q] = (_Float16)1.0f;

  const char* kbase = kimg  + (size_t)h * NT * 16384;
  const char* vbase = vtimg + (size_t)h * NT * 16384;

  f32x16 acc[4];
  f32x16 accl;
#pragma unroll
  for (int dt = 0; dt < 4; ++dt)
#pragma unroll
    for (int r = 0; r < 16; ++r) acc[dt][r] = 0.f;
#pragma unroll
  for (int r = 0; r < 16; ++r) accl[r] = 0.f;
  float m = -1e30f;

#define STAGE(buf, t)                                                          \
  do {                                                                         \
    const char* ks_ = kbase + (size_t)(t) * 16384;                             \
    const char* vs_ = vbase + (size_t)(t) * 16384;                             \
    char* d_ = lds + (buf) * 32768;                                            \
    gload16(ks_ + w * 1024 + lane * 16,          d_ + w * 1024);               \
    gload16(ks_ + (8 + w) * 1024 + lane * 16,    d_ + (8 + w) * 1024);         \
    gload16(vs_ + w * 1024 + lane * 16,          d_ + 16384 + w * 1024);       \
    gload16(vs_ + (8 + w) * 1024 + lane * 16,    d_ + 16384 + (8 + w) * 1024); \
  } while (0)

  STAGE(0, 0);
  asm volatile("s_waitcnt vmcnt(0)");
  __syncthreads();

  int cur = 0;
  for (int t = 0; t < NT; ++t) {
    if (t + 1 < NT) STAGE(cur ^ 1, t + 1);
    const char* kl = lds + cur * 32768;
    const char* vl = kl + 16384;

    // QK^T swapped (32x32): s[jt] = S^T; lane holds q=l31, j=(r&3)+8*(r>>2)+4*hi+32*jt
    f32x16 s[2];
    __builtin_amdgcn_s_setprio(1);
#pragma unroll
    for (int jt = 0; jt < 2; ++jt) {
      f32x16 ss;
#pragma unroll
      for (int r = 0; r < 16; ++r) ss[r] = 0.f;
      const int j = jt * 32 + l31;
#pragma unroll
      for (int dk = 0; dk < 8; ++dk) {
        half8 kf = *(const half8*)(kl + j * 256 + ((dk * 32 + hib * 16) ^ ((l31 & 7) << 4)));
        ss = __builtin_amdgcn_mfma_f32_32x32x16_f16(kf, qf[dk], ss, 0, 0, 0);
      }
      s[jt] = ss;
    }
    __builtin_amdgcn_s_setprio(0);

    // row max: 31 in-lane fmax + 1 cross-half exchange
    float vmax = -1e30f;
#pragma unroll
    for (int jt = 0; jt < 2; ++jt)
#pragma unroll
      for (int r = 0; r < 16; ++r) vmax = fmaxf(vmax, s[jt][r]);
    vmax = fmaxf(vmax, __shfl_xor(vmax, 32));

    // defer-max (log2 domain, THR=8 -> P <= 256 fits f16)
    if (__any(vmax > m + 8.f)) {
      float mn = fmaxf(m, vmax);
      float corr = exp2f(m - mn);
      m = mn;
#pragma unroll
      for (int dt = 0; dt < 4; ++dt)
#pragma unroll
        for (int r = 0; r < 16; ++r) acc[dt][r] *= corr;
#pragma unroll
      for (int r = 0; r < 16; ++r) accl[r] *= corr;
    }

    // P = exp2(S - m), packed; P_pk[jt][rq][h2] = regs (4rq+2h2, 4rq+2h2+1)
    unsigned P_pk[2][4][2];
#pragma unroll
    for (int jt = 0; jt < 2; ++jt)
#pragma unroll
      for (int rq = 0; rq < 4; ++rq)
#pragma unroll
        for (int h2 = 0; h2 < 2; ++h2) {
          float p0 = exp2f(s[jt][4 * rq + 2 * h2]     - m);
          float p1 = exp2f(s[jt][4 * rq + 2 * h2 + 1] - m);
          P_pk[jt][rq][h2] = pkrtz(p0, p1);
        }

    // PV swapped (32x32): acc[dt][d][q] += Vt * P.  B-frag for k-slice ks:
    // j = ks*16 + hi*8 + e; e<4 from lane l31 (regs m=2(ks&1)+hi_dest), e>=4 from l31+32.
#pragma unroll
    for (int ks = 0; ks < 4; ++ks) {
      const int jt = ks >> 1, k1 = ks & 1;
      unsigned send0 = hi ? P_pk[jt][2 * k1][0]     : P_pk[jt][2 * k1 + 1][0];
      unsigned send1 = hi ? P_pk[jt][2 * k1][1]     : P_pk[jt][2 * k1 + 1][1];
      unsigned recv0 = (unsigned)__shfl_xor((int)send0, 32);
      unsigned recv1 = (unsigned)__shfl_xor((int)send1, 32);
      unsigned self0 = hi ? P_pk[jt][2 * k1 + 1][0] : P_pk[jt][2 * k1][0];
      unsigned self1 = hi ? P_pk[jt][2 * k1 + 1][1] : P_pk[jt][2 * k1][1];
      union { unsigned u[4]; half8 hv; } pf;
      pf.u[0] = hi ? recv0 : self0;
      pf.u[1] = hi ? recv1 : self1;
      pf.u[2] = hi ? self0 : recv0;
      pf.u[3] = hi ? self1 : recv1;
      __builtin_amdgcn_s_setprio(1);
#pragma unroll
      for (int dt = 0; dt < 4; ++dt) {
        const int d = dt * 32 + l31;
        half8 vf = *(const half8*)(vl + d * 128 + ((ks * 32 + hib * 16) ^ ((l31 & 7) << 4)));
        acc[dt] = __builtin_amdgcn_mfma_f32_32x32x16_f16(vf, pf.hv, acc[dt], 0, 0, 0);
      }
      accl = __builtin_amdgcn_mfma_f32_32x32x16_f16(ones, pf.hv, accl, 0, 0, 0);
      __builtin_amdgcn_s_setprio(0);
    }

    asm volatile("s_waitcnt vmcnt(0)");
    __syncthreads();
    cur ^= 1;
  }
#undef STAGE

  // epilogue: lane owns O[d][q=l31], d = dt*32 + 8*rq + 4*hi + c; scatter by hmap
  const float rl = 1.0f / accl[0];
  const int qrow = q0 + w * 32 + l31;
  const int srow = hmap[qrow];
  _Float16* ob = att + (size_t)srow * HID + h * HD;
#pragma unroll
  for (int dt = 0; dt < 4; ++dt)
#pragma unroll
    for (int rq = 0; rq < 4; ++rq) {
      const int d0 = dt * 32 + 8 * rq + 4 * hib;
      half4 o;
      o[0] = (_Float16)(acc[dt][4 * rq + 0] * rl);
      o[1] = (_Float16)(acc[dt][4 * rq + 1] * rl);
      o[2] = (_Float16)(acc[dt][4 * rq + 2] * rl);
      o[3] = (_Float16)(acc[dt][4 * rq + 3] * rl);
      *(half4*)(ob + d0) = o;
    }
}

extern "C" void kernel_launch(void* const* d_in, const int* in_sizes, int n_in,
                              void* d_out, int out_size, void* d_ws, size_t ws_size,
                              hipStream_t stream)
{
  const float* x     = (const float*)d_in[0];
  const float* w_qkv = (const float*)d_in[1];
  const float* w_out = (const float*)d_in[2];
  const int*   hmap  = (const int*)d_in[3];
  float* out = (float*)d_out;

  char* ws = (char*)d_ws;
  int* gidx = (int*)ws;                                          ws += 8192;
  _Float16* x16    = (_Float16*)ws;  // aliased with att16 (x16 dead after GEMMs 1a/1b)
  _Float16* att16  = (_Float16*)ws;                              ws += (size_t)S_LEN * HID * 2;
  _Float16* wqkv16 = (_Float16*)ws;                              ws += (size_t)3 * HID * HID * 2;
  _Float16* wout16 = (_Float16*)ws;                              ws += (size_t)HID * HID * 2;
  _Float16* q16    = (_Float16*)ws;                              ws += (size_t)S_LEN * HID * 2;
  _Float16* kv16   = (_Float16*)ws;                              ws += (size_t)NKV * 2 * HID * 2;
  char* kimg  = ws;                                              ws += (size_t)NH * NT * 16384;
  char* vtimg = ws;

  k_build_idx<<<8, 256, 0, stream>>>(hmap, gidx);

  k_cvt_f16<<<(S_LEN * HID / 8 + 255) / 256, 256, 0, stream>>>(x, x16, S_LEN * HID / 8);
  k_cvt_f16<<<(3 * HID * HID / 8 + 255) / 256, 256, 0, stream>>>(w_qkv, wqkv16, 3 * HID * HID / 8);
  k_cvt_f16<<<(HID * HID / 8 + 255) / 256, 256, 0, stream>>>(w_out, wout16, HID * HID / 8);

  // Q = x @ wq^T  (4096 x 2048)
  dim3 gq(HID / 128, S_LEN / 128);
  k_gemm2<false><<<gq, 256, 0, stream>>>(x16, wqkv16, q16, S_LEN, HID, HID, nullptr);
  // KV = x[gidx] @ wkv^T  (2048 x 4096), compact gathered rows
  dim3 gkv(2 * HID / 128, NKV / 128);
  k_gemm2<false><<<gkv, 256, 0, stream>>>(x16, wqkv16 + (size_t)HID * HID, kv16,
                                          NKV, 2 * HID, HID, gidx);

  k_prep<<<NH * NT, 256, 0, stream>>>(kv16, kimg, vtimg);

  k_attn4<<<NH * (S_LEN / QBLK), 512, 65536, stream>>>(q16, kimg, vtimg, hmap, att16);

  // out = att @ w_out^T  (4096 x 2048, fp32)
  dim3 go(HID / 128, S_LEN / 128);
  k_gemm2<true><<<go, 256, 0, stream>>>(att16, wout16, out, S_LEN, HID, HID, nullptr);
}